// Round 3
// baseline (998.610 us; speedup 1.0000x reference)
//
#include <hip/hip_runtime.h>
#include <math.h>

// Problem constants (fixed by setup_inputs)
#define B_ 8
#define C_ 2
#define T_ 1440000
#define F_ 1408            // ceil((T+M)/M) with M=1024
#define R_ 22528           // B*C*F
#define TARGET_HI 2731     // bits > 2730.667  <=>  int bits >= 2731

// ws byte offsets
#define OFF_CFH 0ull                     // f16 [k=1024][n=2048] hi   (4 MiB)
#define OFF_CFL (4ull << 20)             // f16 [k=1024][n=2048] lo   (4 MiB)
#define OFF_CIH (8ull << 20)             // f16 [n=2048][k=1024] hi   (4 MiB)
#define OFF_WF  (12ull << 20)            // f32 [2048]
#define OFF_CF  (13ull << 20)            // f32 [R_][1024] coeffs (92.3 MB)
#define OFF_DQ  (OFF_CF + (size_t)R_ * 1024 * 4)   // f16 [R_][1024] (46 MB)

typedef _Float16 f16x8 __attribute__((ext_vector_type(8)));
typedef _Float16 f16x4 __attribute__((ext_vector_type(4)));
typedef float f32x16 __attribute__((ext_vector_type(16)));

__device__ inline f32x16 mfma16(f16x8 a, f16x8 b, f32x16 c) {
  return __builtin_amdgcn_mfma_f32_32x32x16_f16(a, b, c, 0, 0, 0);
}

// async global->LDS, 16B per lane. LDS dest = uniform base + lane*16.
__device__ inline void gld_lds16(const void* g, void* l) {
  __builtin_amdgcn_global_load_lds(
      (const __attribute__((address_space(1))) void*)g,
      (__attribute__((address_space(3))) void*)l, 16, 0, 0);
}

// ---------------------------------------------------------------- tables ----
// CRITICAL: reproduce the reference's float32 phase arithmetic EXACTLY
// (f32(pi/M) * f32(n+512.5) -> f32 round -> * f32(k+0.5) -> f32 round -> cos).
// Natural layouts (round-0/1): cfh/cfl [k=1024][n=2048], cih [n=2048][k=1024].
// Staging swizzle is applied on the per-lane SOURCE address (rule #21),
// so no special global layout is needed.
__global__ __launch_bounds__(256) void init_tables(char* wsb) {
  _Float16* cfh = (_Float16*)(wsb + OFF_CFH);
  _Float16* cfl = (_Float16*)(wsb + OFF_CFL);
  _Float16* cih = (_Float16*)(wsb + OFF_CIH);
  float*    wf  = (float*)(wsb + OFF_WF);
  int idx = blockIdx.x * 256 + threadIdx.x;
  if (idx < 2097152) {
    int n = idx >> 10, k = idx & 1023;
    const float c0 = (float)(M_PI / 1024.0);
    float a  = (float)n + 0.5f + 512.0f;
    float t1 = c0 * a;
    float ph = t1 * ((float)k + 0.5f);
    float cm = (float)cos((double)ph);          // correctly-rounded cosf
    _Float16 h = (_Float16)cm;
    _Float16 l = (_Float16)(cm - (float)h);
    cfh[(size_t)k * 2048 + n] = h;
    cfl[(size_t)k * 2048 + n] = l;
    cih[(size_t)n * 1024 + k] = h;
  } else if (idx < 2097152 + 2048) {
    int n = idx - 2097152;
    const float c1 = (float)(M_PI / 2048.0);
    float ph = c1 * ((float)n + 0.5f);
    wf[n] = (float)sin((double)ph);
  }
}

// ----------------------------------------------- forward MDCT (f16 3-prod) --
// Double-buffered LDS, ONE barrier per K-step. B tables staged via
// global_load_lds from the k-major table with inv-style source swizzle:
// lane l covers LDS row wid*32+(l>>2), unit l&3; source octet (l&3)^(row&3).
// Read un-permutes with slot ((kc*2+lHalf)^(l31&3))<<4 -> b128 at bank floor.
// A (audio) reg-staged issue-early/write-late (T14). K accumulation order
// identical to round 1 -> bit-identical coeffs (absmax canary 0.06347656).
__global__ __launch_bounds__(256) void fwd_mfma(const float* __restrict__ audio,
                                                const char* __restrict__ wsb,
                                                float* __restrict__ coeffs) {
  __shared__ _Float16 Ah[2][128][40];
  __shared__ _Float16 Al[2][128][40];
  __shared__ __align__(16) _Float16 Bh[2][128][32];
  __shared__ __align__(16) _Float16 Bl[2][128][32];
  const _Float16* cfh = (const _Float16*)(wsb + OFF_CFH);
  const _Float16* cfl = (const _Float16*)(wsb + OFF_CFL);
  const float*    wf  = (const float*)(wsb + OFF_WF);

  int tid = threadIdx.x;
  int lane = tid & 63, wid = tid >> 6;
  int l31 = lane & 31, lHalf = lane >> 5;
  int waveM = wid >> 1, waveN = wid & 1;
  int rowTile = blockIdx.x * 128, colTile = blockIdx.y * 128;

  // A staging coords: 2 threads per row, 16 contiguous K-elems each
  int sRow = tid >> 1;
  int sSeg = (tid & 1) << 4;
  int r = rowTile + sRow, bc = r / F_, f = r - bc * F_;
  const float* __restrict__ aud = audio + (size_t)bc * T_;
  int tBase = (f << 10) - 1024 + sSeg;

  // B staging: wave wid stages LDS rows [wid*32, wid*32+32) (kcol-major),
  // 2 DMAs of 16 rows each. Source row stride 2048 (k-major table).
  int srcRow = lane >> 2;
  int swz = ((lane & 3) ^ (srcRow & 3)) << 3;   // element offset within row
  const _Float16* bhS = cfh + (size_t)(colTile + wid * 32 + srcRow) * 2048 + swz;
  const _Float16* blS = cfl + (size_t)(colTile + wid * 32 + srcRow) * 2048 + swz;

  f32x16 acc[2][2];
#pragma unroll
  for (int i = 0; i < 2; i++)
#pragma unroll
    for (int j = 0; j < 2; j++)
#pragma unroll
      for (int e = 0; e < 16; e++) acc[i][j][e] = 0.f;

  float av[16], wv[16];

  auto loadA = [&](int kt) {
    int t0 = tBase + kt;
    if (t0 >= 0 && t0 + 16 <= T_) {
#pragma unroll
      for (int q = 0; q < 4; q++) {
        float4 x = *(const float4*)(aud + t0 + q * 4);
        av[q * 4 + 0] = x.x; av[q * 4 + 1] = x.y;
        av[q * 4 + 2] = x.z; av[q * 4 + 3] = x.w;
      }
    } else {
#pragma unroll
      for (int i = 0; i < 16; i++) {
        int t = t0 + i;
        av[i] = (t >= 0 && t < T_) ? aud[t] : 0.f;
      }
    }
#pragma unroll
    for (int q = 0; q < 4; q++)
      *(float4*)&wv[q * 4] = *(const float4*)(wf + kt + sSeg + q * 4);
  };

  auto stageB = [&](int kt, int buf) {
    gld_lds16(bhS + kt,             &Bh[buf][wid * 32][0]);
    gld_lds16(bhS + kt + 16 * 2048, &Bh[buf][wid * 32 + 16][0]);
    gld_lds16(blS + kt,             &Bl[buf][wid * 32][0]);
    gld_lds16(blS + kt + 16 * 2048, &Bl[buf][wid * 32 + 16][0]);
  };

  auto writeA = [&](int buf) {
    f16x8 vh[2], vl[2];
#pragma unroll
    for (int i = 0; i < 16; i++) {
      float v = av[i] * wv[i];
      _Float16 h = (_Float16)v;
      vh[i >> 3][i & 7] = h;
      vl[i >> 3][i & 7] = (_Float16)(v - (float)h);
    }
    *(f16x8*)&Ah[buf][sRow][sSeg]     = vh[0];
    *(f16x8*)&Ah[buf][sRow][sSeg + 8] = vh[1];
    *(f16x8*)&Al[buf][sRow][sSeg]     = vl[0];
    *(f16x8*)&Al[buf][sRow][sSeg + 8] = vl[1];
  };

  // prologue: stage kt=0 into buf 0
  loadA(0);
  stageB(0, 0);
  writeA(0);
  asm volatile("s_waitcnt vmcnt(0)" ::: "memory");
  __syncthreads();

  int cur = 0;
  for (int kt = 0; kt < 2048; kt += 32) {
    bool more = (kt + 32) < 2048;
    if (more) {
      loadA(kt + 32);           // audio/window loads in flight over compute
      stageB(kt + 32, cur ^ 1); // B DMAs in flight over compute
    }
#pragma unroll
    for (int kc = 0; kc < 2; kc++) {
      int ko = kc * 16 + lHalf * 8;
      int slot = ((kc * 2 + lHalf) ^ (l31 & 3)) << 4;
      f16x8 a_h[2], a_l[2], b_h[2], b_l[2];
#pragma unroll
      for (int mi = 0; mi < 2; mi++) {
        a_h[mi] = *(const f16x8*)&Ah[cur][waveM * 64 + mi * 32 + l31][ko];
        a_l[mi] = *(const f16x8*)&Al[cur][waveM * 64 + mi * 32 + l31][ko];
      }
#pragma unroll
      for (int ni = 0; ni < 2; ni++) {
        const char* bp = (const char*)&Bh[cur][waveN * 64 + ni * 32 + l31][0];
        const char* bq = (const char*)&Bl[cur][waveN * 64 + ni * 32 + l31][0];
        b_h[ni] = *(const f16x8*)(bp + slot);
        b_l[ni] = *(const f16x8*)(bq + slot);
      }
#pragma unroll
      for (int mi = 0; mi < 2; mi++)
#pragma unroll
        for (int ni = 0; ni < 2; ni++) {
          acc[mi][ni] = mfma16(a_h[mi], b_h[ni], acc[mi][ni]);
          acc[mi][ni] = mfma16(a_h[mi], b_l[ni], acc[mi][ni]);
          acc[mi][ni] = mfma16(a_l[mi], b_h[ni], acc[mi][ni]);
        }
    }
    if (more) writeA(cur ^ 1);
    asm volatile("s_waitcnt vmcnt(0)" ::: "memory");
    __syncthreads();
    cur ^= 1;
  }

  // epilogue: C/D layout col=lane&31, row=(reg&3)+8*(reg>>2)+4*(lane>>5)
#pragma unroll
  for (int mi = 0; mi < 2; mi++)
#pragma unroll
    for (int ni = 0; ni < 2; ni++) {
      int col = colTile + waveN * 64 + ni * 32 + l31;
#pragma unroll
      for (int reg = 0; reg < 16; reg++) {
        int rowIn = (reg & 3) + 8 * (reg >> 2) + 4 * lHalf;
        int rr = rowTile + waveM * 64 + mi * 32 + rowIn;
        coeffs[(size_t)rr * 1024 + col] = acc[mi][ni][reg];
      }
    }
}

// --------------------------------------------- gain search + quant/dequant --
// one WAVE per (b,f) frame; butterfly reduce; powf-free (sqrt/exp2/log2).
__global__ __launch_bounds__(256) void quantize(const float* __restrict__ cf,
                                                _Float16* __restrict__ dqh) {
  int wid = threadIdx.x >> 6, lane = threadIdx.x & 63;
  int bf = blockIdx.x * 4 + wid;     // 4 frames per 256-thread block
  int b = bf / F_, f = bf - b * F_;
  size_t base0 = ((size_t)(b * C_ + 0) * F_ + f) * 1024;
  size_t base1 = ((size_t)(b * C_ + 1) * F_ + f) * 1024;

  float x[32], ax75[32];
#pragma unroll
  for (int c = 0; c < 2; c++) {
    size_t bb = c ? base1 : base0;
#pragma unroll
    for (int j = 0; j < 4; j++) {
      float4 v = *(const float4*)(cf + bb + j * 256 + lane * 4);
      int o = c * 16 + j * 4;
      x[o + 0] = v.x; x[o + 1] = v.y; x[o + 2] = v.z; x[o + 3] = v.w;
    }
  }
#pragma unroll
  for (int u = 0; u < 32; u++) {
    float ax = fabsf(x[u]);
    float s  = sqrtf(ax);
    ax75[u]  = s * sqrtf(s);         // |x|^0.75
  }

  int lo = 0, hi = 120;
#pragma unroll
  for (int it = 0; it < 8; it++) {
    int mid = (lo + hi) >> 1;
    float inv = exp2f(-0.1875f * (float)mid);
    int s = 0;
#pragma unroll
    for (int u = 0; u < 32; u++) {
      float qm = rintf(ax75[u] * inv);
      int iq = (int)qm;
      s += (iq > 0) ? (33 - __clz(iq)) : 1;
    }
#pragma unroll
    for (int off = 1; off < 64; off <<= 1) s += __shfl_xor(s, off, 64);
    if (s >= TARGET_HI) lo = mid + 1; else hi = mid;   // uniform per wave
  }

  float scale = exp2f(0.25f * (float)hi);
  float rs    = exp2f(-0.25f * (float)hi);
#pragma unroll
  for (int c = 0; c < 2; c++) {
    size_t bb = c ? base1 : base0;
#pragma unroll
    for (int j = 0; j < 4; j++) {
      f16x4 o4;
#pragma unroll
      for (int e = 0; e < 4; e++) {
        int u = c * 16 + j * 4 + e;
        float ax  = fabsf(x[u]);
        float t   = ax * rs + 1e-9f;
        float s1  = sqrtf(t);
        float qs  = s1 * sqrtf(s1);              // (|x|/scale+eps)^0.75
        float q   = rintf(qs);
        float q43 = q * exp2f(__log2f(q) * (1.0f / 3.0f));  // q^(4/3)
        o4[e] = (_Float16)copysignf(q43 * scale, x[u]);
      }
      *(f16x4*)(dqh + bb + j * 256 + lane * 4) = o4;
    }
  }
}

// --------------------------------------- inverse MDCT (f16 1-prod) + OLA ----
// BK=32, DOUBLE-buffered (48 KB, 3 blocks/CU), minimum-2-phase:
// stage(next) issued BEFORE compute(cur), one vmcnt(0)+barrier per tile.
// Source-address XOR swizzle (64B rows, 4 units, row&3) -> b128 reads at floor.
__global__ __launch_bounds__(256) void inv_mfma(const char* __restrict__ wsb,
                                               float* __restrict__ out) {
  __shared__ __align__(16) _Float16 Ad[2][128][32];   // 2 x 8 KB
  __shared__ __align__(16) _Float16 Bd[2][256][32];   // 2 x 16 KB
  const _Float16* dqh = (const _Float16*)(wsb + OFF_DQ);
  const _Float16* cih = (const _Float16*)(wsb + OFF_CIH);
  const float*    wf  = (const float*)(wsb + OFF_WF);

  int tid = threadIdx.x;
  int lane = tid & 63, wid = tid >> 6;
  int l31 = lane & 31, lHalf = lane >> 5;
  int waveM = wid >> 1, waveN = wid & 1;
  int rowTile = blockIdx.x * 128, colTile = blockIdx.y * 256;

  // staging: rows of 32 f16 (64B = 4 16B-units); lane l covers row l>>2,
  // unit slot l&3; source element offset XOR-swizzled by (row&3).
  int srcRow = lane >> 2;
  int swz = ((lane & 3) ^ (srcRow & 3)) << 3;
  const _Float16* aS = dqh + (size_t)(rowTile + wid * 32 + srcRow) * 1024 + swz;
  const _Float16* bS = cih + (size_t)(colTile + wid * 64 + srcRow) * 1024 + swz;

  auto stage = [&](int kt, int buf) {
    gld_lds16(aS + kt,             &Ad[buf][wid * 32][0]);
    gld_lds16(aS + kt + 16 * 1024, &Ad[buf][wid * 32 + 16][0]);
#pragma unroll
    for (int j = 0; j < 4; j++)
      gld_lds16(bS + kt + (size_t)j * 16 * 1024, &Bd[buf][wid * 64 + j * 16][0]);
  };

  f32x16 acc[2][4];
#pragma unroll
  for (int i = 0; i < 2; i++)
#pragma unroll
    for (int j = 0; j < 4; j++)
#pragma unroll
      for (int e = 0; e < 16; e++) acc[i][j][e] = 0.f;

  stage(0, 0);
  asm volatile("s_waitcnt vmcnt(0)" ::: "memory");
  __syncthreads();

  int cur = 0;
  for (int kt = 0; kt < 1024; kt += 32) {
    if (kt + 32 < 1024) stage(kt + 32, cur ^ 1);
#pragma unroll
    for (int kc = 0; kc < 2; kc++) {
      int slot = ((kc * 2 + lHalf) ^ (l31 & 3)) << 4;
      const char* ar = (const char*)&Ad[cur][waveM * 64 + l31][0];
      const char* br = (const char*)&Bd[cur][waveN * 128 + l31][0];
      f16x8 a0 = *(const f16x8*)(ar + slot);
      f16x8 a1 = *(const f16x8*)(ar + 32 * 64 + slot);
      f16x8 b0 = *(const f16x8*)(br + slot);
      f16x8 b1 = *(const f16x8*)(br + 32 * 64 + slot);
      f16x8 b2 = *(const f16x8*)(br + 64 * 64 + slot);
      f16x8 b3 = *(const f16x8*)(br + 96 * 64 + slot);
      acc[0][0] = mfma16(a0, b0, acc[0][0]);
      acc[0][1] = mfma16(a0, b1, acc[0][1]);
      acc[0][2] = mfma16(a0, b2, acc[0][2]);
      acc[0][3] = mfma16(a0, b3, acc[0][3]);
      acc[1][0] = mfma16(a1, b0, acc[1][0]);
      acc[1][1] = mfma16(a1, b1, acc[1][1]);
      acc[1][2] = mfma16(a1, b2, acc[1][2]);
      acc[1][3] = mfma16(a1, b3, acc[1][3]);
    }
    asm volatile("s_waitcnt vmcnt(0)" ::: "memory");
    __syncthreads();
    cur ^= 1;
  }

  const float sc = 2.0f / 1024.0f;
#pragma unroll
  for (int mi = 0; mi < 2; mi++)
#pragma unroll
    for (int ni = 0; ni < 4; ni++) {
      int n = colTile + waveN * 128 + ni * 32 + l31;
      float wv = wf[n] * sc;
#pragma unroll
      for (int reg = 0; reg < 16; reg++) {
        int rowIn = (reg & 3) + 8 * (reg >> 2) + 4 * lHalf;
        int rr = rowTile + waveM * 64 + mi * 32 + rowIn;
        int bc = rr / F_;
        int f  = rr - bc * F_;
        int t  = (f << 10) + n - 1024;
        if (t >= 0 && t < T_)
          unsafeAtomicAdd(out + (size_t)bc * T_ + t, acc[mi][ni][reg] * wv);
      }
    }
}

// ------------------------------------------------------------------ launch --
extern "C" void kernel_launch(void* const* d_in, const int* in_sizes, int n_in,
                              void* d_out, int out_size, void* d_ws, size_t ws_size,
                              hipStream_t stream) {
  const float* audio = (const float*)d_in[0];
  float* out = (float*)d_out;
  char* wsb  = (char*)d_ws;
  float*    cf  = (float*)(wsb + OFF_CF);
  _Float16* dqh = (_Float16*)(wsb + OFF_DQ);

  hipMemsetAsync(d_out, 0, (size_t)out_size * sizeof(float), stream);
  init_tables<<<(2097152 + 2048 + 255) / 256, 256, 0, stream>>>(wsb);
  fwd_mfma<<<dim3(R_ / 128, 1024 / 128), 256, 0, stream>>>(audio, wsb, cf);
  quantize<<<(B_ * F_) / 4, 256, 0, stream>>>(cf, dqh);
  inv_mfma<<<dim3(R_ / 128, 2048 / 256), 256, 0, stream>>>(wsb, out);
}

// Round 4
// 966.817 us; speedup vs baseline: 1.0329x; 1.0329x over previous
//
#include <hip/hip_runtime.h>
#include <math.h>

// Problem constants (fixed by setup_inputs)
#define B_ 8
#define C_ 2
#define T_ 1440000
#define F_ 1408            // ceil((T+M)/M) with M=1024
#define R_ 22528           // B*C*F
#define TARGET_HI 2731     // bits > 2730.667  <=>  int bits >= 2731

// ws byte offsets
#define OFF_CFH 0ull                     // f16 [k=1024][n=2048] hi   (4 MiB)
#define OFF_CFL (4ull << 20)             // f16 [k=1024][n=2048] lo   (4 MiB)
#define OFF_CIH (8ull << 20)             // f16 [n=2048][k=1024] hi   (4 MiB)
#define OFF_WF  (12ull << 20)            // f32 [2048]
#define OFF_CF  (13ull << 20)            // f32 [R_][1024] coeffs (92.3 MB)
#define OFF_DQ  (OFF_CF + (size_t)R_ * 1024 * 4)   // f16 [R_][1024] (46 MB)

typedef _Float16 f16x8 __attribute__((ext_vector_type(8)));
typedef _Float16 f16x4 __attribute__((ext_vector_type(4)));
typedef float f32x16 __attribute__((ext_vector_type(16)));

__device__ inline f32x16 mfma16(f16x8 a, f16x8 b, f32x16 c) {
  return __builtin_amdgcn_mfma_f32_32x32x16_f16(a, b, c, 0, 0, 0);
}

// async global->LDS, 16B per lane. LDS dest = uniform base + lane*16.
__device__ inline void gld_lds16(const void* g, void* l) {
  __builtin_amdgcn_global_load_lds(
      (const __attribute__((address_space(1))) void*)g,
      (__attribute__((address_space(3))) void*)l, 16, 0, 0);
}

// Swizzle rule for [rows][32] f16 LDS tiles (64B rows, 4 16B units/row):
//   k-octet u of row r lives at slot  u ^ ((r>>1)&3).
// Position index (r&1)*4 + slot is a bijection onto 0..7 over any aligned
// 8-row run -> every 8 consecutive lanes of a b128 read/DMA-source cover all
// 32 banks (same invariant as the proven [128][40] stagger). The round-3
// (r&3) XOR covered only 16 banks per half-wave -> 2x conflicts (measured).

// ---------------------------------------------------------------- tables ----
// CRITICAL: reproduce the reference's float32 phase arithmetic EXACTLY
// (f32(pi/M) * f32(n+512.5) -> f32 round -> * f32(k+0.5) -> f32 round -> cos).
__global__ __launch_bounds__(256) void init_tables(char* wsb) {
  _Float16* cfh = (_Float16*)(wsb + OFF_CFH);
  _Float16* cfl = (_Float16*)(wsb + OFF_CFL);
  _Float16* cih = (_Float16*)(wsb + OFF_CIH);
  float*    wf  = (float*)(wsb + OFF_WF);
  int idx = blockIdx.x * 256 + threadIdx.x;
  if (idx < 2097152) {
    int n = idx >> 10, k = idx & 1023;
    const float c0 = (float)(M_PI / 1024.0);
    float a  = (float)n + 0.5f + 512.0f;
    float t1 = c0 * a;
    float ph = t1 * ((float)k + 0.5f);
    float cm = (float)cos((double)ph);          // correctly-rounded cosf
    _Float16 h = (_Float16)cm;
    _Float16 l = (_Float16)(cm - (float)h);
    cfh[(size_t)k * 2048 + n] = h;
    cfl[(size_t)k * 2048 + n] = l;
    cih[(size_t)n * 1024 + k] = h;
  } else if (idx < 2097152 + 2048) {
    int n = idx - 2097152;
    const float c1 = (float)(M_PI / 2048.0);
    float ph = c1 * ((float)n + 0.5f);
    wf[n] = (float)sin((double)ph);
  }
}

// ----------------------------------------------- forward MDCT (f16 3-prod) --
// Double-buffered LDS, ONE barrier per K-step. B via global_load_lds with
// the corrected source swizzle; A reg-staged issue-early/write-late.
// K accumulation order identical to round 0/1 -> absmax canary 0.06347656.
__global__ __launch_bounds__(256) void fwd_mfma(const float* __restrict__ audio,
                                                const char* __restrict__ wsb,
                                                float* __restrict__ coeffs) {
  __shared__ _Float16 Ah[2][128][40];
  __shared__ _Float16 Al[2][128][40];
  __shared__ __align__(16) _Float16 Bh[2][128][32];
  __shared__ __align__(16) _Float16 Bl[2][128][32];
  const _Float16* cfh = (const _Float16*)(wsb + OFF_CFH);
  const _Float16* cfl = (const _Float16*)(wsb + OFF_CFL);
  const float*    wf  = (const float*)(wsb + OFF_WF);

  int tid = threadIdx.x;
  int lane = tid & 63, wid = tid >> 6;
  int l31 = lane & 31, lHalf = lane >> 5;
  int waveM = wid >> 1, waveN = wid & 1;
  int rowTile = blockIdx.x * 128, colTile = blockIdx.y * 128;

  // A staging coords: 2 threads per row, 16 contiguous K-elems each
  int sRow = tid >> 1;
  int sSeg = (tid & 1) << 4;
  int r = rowTile + sRow, bc = r / F_, f = r - bc * F_;
  const float* __restrict__ aud = audio + (size_t)bc * T_;
  int tBase = (f << 10) - 1024 + sSeg;

  // B staging: wave wid stages LDS rows [wid*32, wid*32+32), 2 DMAs x 16 rows.
  // lane l -> row (l>>2), slot (l&3); source octet (l&3)^((row>>1)&3).
  int srcRow = lane >> 2;
  int swz = ((lane & 3) ^ ((lane >> 3) & 3)) << 3;   // element offset in row
  const _Float16* bhS = cfh + (size_t)(colTile + wid * 32 + srcRow) * 2048 + swz;
  const _Float16* blS = cfl + (size_t)(colTile + wid * 32 + srcRow) * 2048 + swz;

  f32x16 acc[2][2];
#pragma unroll
  for (int i = 0; i < 2; i++)
#pragma unroll
    for (int j = 0; j < 2; j++)
#pragma unroll
      for (int e = 0; e < 16; e++) acc[i][j][e] = 0.f;

  float av[16], wv[16];

  auto loadA = [&](int kt) {
    int t0 = tBase + kt;
    if (t0 >= 0 && t0 + 16 <= T_) {
#pragma unroll
      for (int q = 0; q < 4; q++) {
        float4 x = *(const float4*)(aud + t0 + q * 4);
        av[q * 4 + 0] = x.x; av[q * 4 + 1] = x.y;
        av[q * 4 + 2] = x.z; av[q * 4 + 3] = x.w;
      }
    } else {
#pragma unroll
      for (int i = 0; i < 16; i++) {
        int t = t0 + i;
        av[i] = (t >= 0 && t < T_) ? aud[t] : 0.f;
      }
    }
#pragma unroll
    for (int q = 0; q < 4; q++)
      *(float4*)&wv[q * 4] = *(const float4*)(wf + kt + sSeg + q * 4);
  };

  auto stageB = [&](int kt, int buf) {
    gld_lds16(bhS + kt,             &Bh[buf][wid * 32][0]);
    gld_lds16(bhS + kt + 16 * 2048, &Bh[buf][wid * 32 + 16][0]);
    gld_lds16(blS + kt,             &Bl[buf][wid * 32][0]);
    gld_lds16(blS + kt + 16 * 2048, &Bl[buf][wid * 32 + 16][0]);
  };

  auto writeA = [&](int buf) {
    f16x8 vh[2], vl[2];
#pragma unroll
    for (int i = 0; i < 16; i++) {
      float v = av[i] * wv[i];
      _Float16 h = (_Float16)v;
      vh[i >> 3][i & 7] = h;
      vl[i >> 3][i & 7] = (_Float16)(v - (float)h);
    }
    *(f16x8*)&Ah[buf][sRow][sSeg]     = vh[0];
    *(f16x8*)&Ah[buf][sRow][sSeg + 8] = vh[1];
    *(f16x8*)&Al[buf][sRow][sSeg]     = vl[0];
    *(f16x8*)&Al[buf][sRow][sSeg + 8] = vl[1];
  };

  // prologue: stage kt=0 into buf 0
  loadA(0);
  stageB(0, 0);
  writeA(0);
  asm volatile("s_waitcnt vmcnt(0)" ::: "memory");
  __syncthreads();

  int cur = 0;
  for (int kt = 0; kt < 2048; kt += 32) {
    bool more = (kt + 32) < 2048;
    if (more) {
      loadA(kt + 32);           // audio/window loads in flight over compute
      stageB(kt + 32, cur ^ 1); // B DMAs in flight over compute
    }
#pragma unroll
    for (int kc = 0; kc < 2; kc++) {
      int ko = kc * 16 + lHalf * 8;
      int slot = ((kc * 2 + lHalf) ^ ((l31 >> 1) & 3)) << 4;  // corrected swz
      f16x8 a_h[2], a_l[2], b_h[2], b_l[2];
#pragma unroll
      for (int mi = 0; mi < 2; mi++) {
        a_h[mi] = *(const f16x8*)&Ah[cur][waveM * 64 + mi * 32 + l31][ko];
        a_l[mi] = *(const f16x8*)&Al[cur][waveM * 64 + mi * 32 + l31][ko];
      }
#pragma unroll
      for (int ni = 0; ni < 2; ni++) {
        const char* bp = (const char*)&Bh[cur][waveN * 64 + ni * 32 + l31][0];
        const char* bq = (const char*)&Bl[cur][waveN * 64 + ni * 32 + l31][0];
        b_h[ni] = *(const f16x8*)(bp + slot);
        b_l[ni] = *(const f16x8*)(bq + slot);
      }
#pragma unroll
      for (int mi = 0; mi < 2; mi++)
#pragma unroll
        for (int ni = 0; ni < 2; ni++) {
          acc[mi][ni] = mfma16(a_h[mi], b_h[ni], acc[mi][ni]);
          acc[mi][ni] = mfma16(a_h[mi], b_l[ni], acc[mi][ni]);
          acc[mi][ni] = mfma16(a_l[mi], b_h[ni], acc[mi][ni]);
        }
    }
    if (more) writeA(cur ^ 1);
    asm volatile("s_waitcnt vmcnt(0)" ::: "memory");
    __syncthreads();
    cur ^= 1;
  }

  // epilogue: C/D layout col=lane&31, row=(reg&3)+8*(reg>>2)+4*(lane>>5)
#pragma unroll
  for (int mi = 0; mi < 2; mi++)
#pragma unroll
    for (int ni = 0; ni < 2; ni++) {
      int col = colTile + waveN * 64 + ni * 32 + l31;
#pragma unroll
      for (int reg = 0; reg < 16; reg++) {
        int rowIn = (reg & 3) + 8 * (reg >> 2) + 4 * lHalf;
        int rr = rowTile + waveM * 64 + mi * 32 + rowIn;
        coeffs[(size_t)rr * 1024 + col] = acc[mi][ni][reg];
      }
    }
}

// --------------------------------------------- gain search + quant/dequant --
// one WAVE per (b,f) frame; butterfly reduce; powf-free (sqrt/exp2/log2).
__global__ __launch_bounds__(256) void quantize(const float* __restrict__ cf,
                                                _Float16* __restrict__ dqh) {
  int wid = threadIdx.x >> 6, lane = threadIdx.x & 63;
  int bf = blockIdx.x * 4 + wid;     // 4 frames per 256-thread block
  int b = bf / F_, f = bf - b * F_;
  size_t base0 = ((size_t)(b * C_ + 0) * F_ + f) * 1024;
  size_t base1 = ((size_t)(b * C_ + 1) * F_ + f) * 1024;

  float x[32], ax75[32];
#pragma unroll
  for (int c = 0; c < 2; c++) {
    size_t bb = c ? base1 : base0;
#pragma unroll
    for (int j = 0; j < 4; j++) {
      float4 v = *(const float4*)(cf + bb + j * 256 + lane * 4);
      int o = c * 16 + j * 4;
      x[o + 0] = v.x; x[o + 1] = v.y; x[o + 2] = v.z; x[o + 3] = v.w;
    }
  }
#pragma unroll
  for (int u = 0; u < 32; u++) {
    float ax = fabsf(x[u]);
    float s  = sqrtf(ax);
    ax75[u]  = s * sqrtf(s);         // |x|^0.75
  }

  int lo = 0, hi = 120;
#pragma unroll
  for (int it = 0; it < 8; it++) {
    int mid = (lo + hi) >> 1;
    float inv = exp2f(-0.1875f * (float)mid);
    int s = 0;
#pragma unroll
    for (int u = 0; u < 32; u++) {
      float qm = rintf(ax75[u] * inv);
      int iq = (int)qm;
      s += (iq > 0) ? (33 - __clz(iq)) : 1;
    }
#pragma unroll
    for (int off = 1; off < 64; off <<= 1) s += __shfl_xor(s, off, 64);
    if (s >= TARGET_HI) lo = mid + 1; else hi = mid;   // uniform per wave
  }

  float scale = exp2f(0.25f * (float)hi);
  float rs    = exp2f(-0.25f * (float)hi);
#pragma unroll
  for (int c = 0; c < 2; c++) {
    size_t bb = c ? base1 : base0;
#pragma unroll
    for (int j = 0; j < 4; j++) {
      f16x4 o4;
#pragma unroll
      for (int e = 0; e < 4; e++) {
        int u = c * 16 + j * 4 + e;
        float ax  = fabsf(x[u]);
        float t   = ax * rs + 1e-9f;
        float s1  = sqrtf(t);
        float qs  = s1 * sqrtf(s1);              // (|x|/scale+eps)^0.75
        float q   = rintf(qs);
        float q43 = q * exp2f(__log2f(q) * (1.0f / 3.0f));  // q^(4/3)
        o4[e] = (_Float16)copysignf(q43 * scale, x[u]);
      }
      *(f16x4*)(dqh + bb + j * 256 + lane * 4) = o4;
    }
  }
}

// --------------------------------------- inverse MDCT (f16 1-prod) + OLA ----
// BK=32, DOUBLE-buffered (48 KB, 3 blocks/CU), stage(next) before compute(cur),
// one vmcnt(0)+barrier per tile. Corrected (row>>1)&3 swizzle.
__global__ __launch_bounds__(256) void inv_mfma(const char* __restrict__ wsb,
                                               float* __restrict__ out) {
  __shared__ __align__(16) _Float16 Ad[2][128][32];   // 2 x 8 KB
  __shared__ __align__(16) _Float16 Bd[2][256][32];   // 2 x 16 KB
  const _Float16* dqh = (const _Float16*)(wsb + OFF_DQ);
  const _Float16* cih = (const _Float16*)(wsb + OFF_CIH);
  const float*    wf  = (const float*)(wsb + OFF_WF);

  int tid = threadIdx.x;
  int lane = tid & 63, wid = tid >> 6;
  int l31 = lane & 31, lHalf = lane >> 5;
  int waveM = wid >> 1, waveN = wid & 1;
  int rowTile = blockIdx.x * 128, colTile = blockIdx.y * 256;

  // staging: lane l covers row l>>2, slot l&3; source octet (l&3)^((row>>1)&3)
  int srcRow = lane >> 2;
  int swz = ((lane & 3) ^ ((lane >> 3) & 3)) << 3;
  const _Float16* aS = dqh + (size_t)(rowTile + wid * 32 + srcRow) * 1024 + swz;
  const _Float16* bS = cih + (size_t)(colTile + wid * 64 + srcRow) * 1024 + swz;

  auto stage = [&](int kt, int buf) {
    gld_lds16(aS + kt,             &Ad[buf][wid * 32][0]);
    gld_lds16(aS + kt + 16 * 1024, &Ad[buf][wid * 32 + 16][0]);
#pragma unroll
    for (int j = 0; j < 4; j++)
      gld_lds16(bS + kt + (size_t)j * 16 * 1024, &Bd[buf][wid * 64 + j * 16][0]);
  };

  f32x16 acc[2][4];
#pragma unroll
  for (int i = 0; i < 2; i++)
#pragma unroll
    for (int j = 0; j < 4; j++)
#pragma unroll
      for (int e = 0; e < 16; e++) acc[i][j][e] = 0.f;

  stage(0, 0);
  asm volatile("s_waitcnt vmcnt(0)" ::: "memory");
  __syncthreads();

  int cur = 0;
  for (int kt = 0; kt < 1024; kt += 32) {
    if (kt + 32 < 1024) stage(kt + 32, cur ^ 1);
#pragma unroll
    for (int kc = 0; kc < 2; kc++) {
      int slot = ((kc * 2 + lHalf) ^ ((l31 >> 1) & 3)) << 4;  // corrected swz
      const char* ar = (const char*)&Ad[cur][waveM * 64 + l31][0];
      const char* br = (const char*)&Bd[cur][waveN * 128 + l31][0];
      f16x8 a0 = *(const f16x8*)(ar + slot);
      f16x8 a1 = *(const f16x8*)(ar + 32 * 64 + slot);
      f16x8 b0 = *(const f16x8*)(br + slot);
      f16x8 b1 = *(const f16x8*)(br + 32 * 64 + slot);
      f16x8 b2 = *(const f16x8*)(br + 64 * 64 + slot);
      f16x8 b3 = *(const f16x8*)(br + 96 * 64 + slot);
      acc[0][0] = mfma16(a0, b0, acc[0][0]);
      acc[0][1] = mfma16(a0, b1, acc[0][1]);
      acc[0][2] = mfma16(a0, b2, acc[0][2]);
      acc[0][3] = mfma16(a0, b3, acc[0][3]);
      acc[1][0] = mfma16(a1, b0, acc[1][0]);
      acc[1][1] = mfma16(a1, b1, acc[1][1]);
      acc[1][2] = mfma16(a1, b2, acc[1][2]);
      acc[1][3] = mfma16(a1, b3, acc[1][3]);
    }
    asm volatile("s_waitcnt vmcnt(0)" ::: "memory");
    __syncthreads();
    cur ^= 1;
  }

  const float sc = 2.0f / 1024.0f;
#pragma unroll
  for (int mi = 0; mi < 2; mi++)
#pragma unroll
    for (int ni = 0; ni < 4; ni++) {
      int n = colTile + waveN * 128 + ni * 32 + l31;
      float wv = wf[n] * sc;
#pragma unroll
      for (int reg = 0; reg < 16; reg++) {
        int rowIn = (reg & 3) + 8 * (reg >> 2) + 4 * lHalf;
        int rr = rowTile + waveM * 64 + mi * 32 + rowIn;
        int bc = rr / F_;
        int f  = rr - bc * F_;
        int t  = (f << 10) + n - 1024;
        if (t >= 0 && t < T_)
          unsafeAtomicAdd(out + (size_t)bc * T_ + t, acc[mi][ni][reg] * wv);
      }
    }
}

// ------------------------------------------------------------------ launch --
extern "C" void kernel_launch(void* const* d_in, const int* in_sizes, int n_in,
                              void* d_out, int out_size, void* d_ws, size_t ws_size,
                              hipStream_t stream) {
  const float* audio = (const float*)d_in[0];
  float* out = (float*)d_out;
  char* wsb  = (char*)d_ws;
  float*    cf  = (float*)(wsb + OFF_CF);
  _Float16* dqh = (_Float16*)(wsb + OFF_DQ);

  hipMemsetAsync(d_out, 0, (size_t)out_size * sizeof(float), stream);
  init_tables<<<(2097152 + 2048 + 255) / 256, 256, 0, stream>>>(wsb);
  fwd_mfma<<<dim3(R_ / 128, 1024 / 128), 256, 0, stream>>>(audio, wsb, cf);
  quantize<<<(B_ * F_) / 4, 256, 0, stream>>>(cf, dqh);
  inv_mfma<<<dim3(R_ / 128, 2048 / 256), 256, 0, stream>>>(wsb, out);
}

// Round 5
// 798.121 us; speedup vs baseline: 1.2512x; 1.2114x over previous
//
#include <hip/hip_runtime.h>
#include <math.h>

// Problem constants (fixed by setup_inputs)
#define B_ 8
#define C_ 2
#define T_ 1440000
#define F_ 1408            // ceil((T+M)/M) with M=1024
#define R_ 22528           // B*C*F
#define TARGET_HI 2731     // bits > 2730.667  <=>  int bits >= 2731

// ws byte offsets
#define OFF_CFH 0ull                     // f16 [k=1024][n=2048] hi   (4 MiB)
#define OFF_CFL (4ull << 20)             // f16 [k=1024][n=2048] lo   (4 MiB)
#define OFF_CIH (8ull << 20)             // f16 [n=2048][k=1024] hi   (4 MiB)
#define OFF_WF  (12ull << 20)            // f32 [2048]
#define OFF_CF  (13ull << 20)            // f32 [R_][1024] coeffs; REUSED as f16 td [R_][2048] (92.3 MB)
#define OFF_DQ  (OFF_CF + (size_t)R_ * 1024 * 4)   // f16 [R_][1024] (46 MB)

typedef _Float16 f16x8 __attribute__((ext_vector_type(8)));
typedef _Float16 f16x4 __attribute__((ext_vector_type(4)));
typedef float f32x16 __attribute__((ext_vector_type(16)));

__device__ inline f32x16 mfma16(f16x8 a, f16x8 b, f32x16 c) {
  return __builtin_amdgcn_mfma_f32_32x32x16_f16(a, b, c, 0, 0, 0);
}

// async global->LDS, 16B per lane. LDS dest = uniform base + lane*16.
__device__ inline void gld_lds16(const void* g, void* l) {
  __builtin_amdgcn_global_load_lds(
      (const __attribute__((address_space(1))) void*)g,
      (__attribute__((address_space(3))) void*)l, 16, 0, 0);
}

// ---------------------------------------------------------------- tables ----
// CRITICAL: reproduce the reference's float32 phase arithmetic EXACTLY
// (f32(pi/M) * f32(n+512.5) -> f32 round -> * f32(k+0.5) -> f32 round -> cos).
__global__ __launch_bounds__(256) void init_tables(char* wsb) {
  _Float16* cfh = (_Float16*)(wsb + OFF_CFH);
  _Float16* cfl = (_Float16*)(wsb + OFF_CFL);
  _Float16* cih = (_Float16*)(wsb + OFF_CIH);
  float*    wf  = (float*)(wsb + OFF_WF);
  int idx = blockIdx.x * 256 + threadIdx.x;
  if (idx < 2097152) {
    int n = idx >> 10, k = idx & 1023;
    const float c0 = (float)(M_PI / 1024.0);
    float a  = (float)n + 0.5f + 512.0f;
    float t1 = c0 * a;
    float ph = t1 * ((float)k + 0.5f);
    float cm = (float)cos((double)ph);          // correctly-rounded cosf
    _Float16 h = (_Float16)cm;
    _Float16 l = (_Float16)(cm - (float)h);
    cfh[(size_t)k * 2048 + n] = h;
    cfl[(size_t)k * 2048 + n] = l;
    cih[(size_t)n * 1024 + k] = h;
  } else if (idx < 2097152 + 2048) {
    int n = idx - 2097152;
    const float c1 = (float)(M_PI / 2048.0);
    float ph = c1 * ((float)n + 0.5f);
    wf[n] = (float)sin((double)ph);
  }
}

// ----------------------------------------------- forward MDCT (f16 3-prod) --
// REVERTED to the round-0 structure (measured 388 us, MfmaUtil 33%, 40 KB LDS,
// 4 blocks/CU). Round-3/4 dbuf experiment: 72 KB LDS -> 2 blocks/CU ->
// occupancy 26.9->20.8% -> 500 us despite fewer barriers (m132 signature).
__global__ __launch_bounds__(256) void fwd_mfma(const float* __restrict__ audio,
                                                const char* __restrict__ wsb,
                                                float* __restrict__ coeffs) {
  __shared__ _Float16 Ah[128][40];
  __shared__ _Float16 Al[128][40];
  __shared__ _Float16 Bh[128][40];
  __shared__ _Float16 Bl[128][40];
  const _Float16* cfh = (const _Float16*)(wsb + OFF_CFH);
  const _Float16* cfl = (const _Float16*)(wsb + OFF_CFL);
  const float*    wf  = (const float*)(wsb + OFF_WF);

  int tid = threadIdx.x;
  int lane = tid & 63, wid = tid >> 6;
  int l31 = lane & 31, lHalf = lane >> 5;
  int waveM = wid >> 1, waveN = wid & 1;
  int rowTile = blockIdx.x * 128, colTile = blockIdx.y * 128;

  int sRow = tid >> 1;
  int sSeg = (tid & 1) << 4;
  int r = rowTile + sRow, bc = r / F_, f = r - bc * F_;
  const float* __restrict__ aud = audio + (size_t)bc * T_;
  int tBase = (f << 10) - 1024 + sSeg;
  const _Float16* bhp = cfh + (size_t)(colTile + sRow) * 2048 + sSeg;
  const _Float16* blp = cfl + (size_t)(colTile + sRow) * 2048 + sSeg;

  f32x16 acc[2][2];
#pragma unroll
  for (int i = 0; i < 2; i++)
#pragma unroll
    for (int j = 0; j < 2; j++)
#pragma unroll
      for (int e = 0; e < 16; e++) acc[i][j][e] = 0.f;

  for (int kt = 0; kt < 2048; kt += 32) {
    float av[16];
    int t0 = tBase + kt;
    if (t0 >= 0 && t0 + 16 <= T_) {
#pragma unroll
      for (int q = 0; q < 4; q++) {
        float4 x = *(const float4*)(aud + t0 + q * 4);
        av[q * 4 + 0] = x.x; av[q * 4 + 1] = x.y;
        av[q * 4 + 2] = x.z; av[q * 4 + 3] = x.w;
      }
    } else {
#pragma unroll
      for (int i = 0; i < 16; i++) {
        int t = t0 + i;
        av[i] = (t >= 0 && t < T_) ? aud[t] : 0.f;
      }
    }
    f16x8 vh[2], vl[2];
#pragma unroll
    for (int i = 0; i < 16; i++) {
      float v = av[i] * wf[kt + sSeg + i];
      _Float16 h = (_Float16)v;
      vh[i >> 3][i & 7] = h;
      vl[i >> 3][i & 7] = (_Float16)(v - (float)h);
    }
    float4 tb0 = *(const float4*)(bhp + kt);
    float4 tb1 = *(const float4*)(bhp + kt + 8);
    float4 tl0 = *(const float4*)(blp + kt);
    float4 tl1 = *(const float4*)(blp + kt + 8);

    __syncthreads();
    *(f16x8*)&Ah[sRow][sSeg]     = vh[0];
    *(f16x8*)&Ah[sRow][sSeg + 8] = vh[1];
    *(f16x8*)&Al[sRow][sSeg]     = vl[0];
    *(f16x8*)&Al[sRow][sSeg + 8] = vl[1];
    *(float4*)&Bh[sRow][sSeg]     = tb0;
    *(float4*)&Bh[sRow][sSeg + 8] = tb1;
    *(float4*)&Bl[sRow][sSeg]     = tl0;
    *(float4*)&Bl[sRow][sSeg + 8] = tl1;
    __syncthreads();

#pragma unroll
    for (int kc = 0; kc < 2; kc++) {
      int ko = kc * 16 + lHalf * 8;
      f16x8 a_h[2], a_l[2], b_h[2], b_l[2];
#pragma unroll
      for (int mi = 0; mi < 2; mi++) {
        a_h[mi] = *(const f16x8*)&Ah[waveM * 64 + mi * 32 + l31][ko];
        a_l[mi] = *(const f16x8*)&Al[waveM * 64 + mi * 32 + l31][ko];
      }
#pragma unroll
      for (int ni = 0; ni < 2; ni++) {
        b_h[ni] = *(const f16x8*)&Bh[waveN * 64 + ni * 32 + l31][ko];
        b_l[ni] = *(const f16x8*)&Bl[waveN * 64 + ni * 32 + l31][ko];
      }
#pragma unroll
      for (int mi = 0; mi < 2; mi++)
#pragma unroll
        for (int ni = 0; ni < 2; ni++) {
          acc[mi][ni] = mfma16(a_h[mi], b_h[ni], acc[mi][ni]);
          acc[mi][ni] = mfma16(a_h[mi], b_l[ni], acc[mi][ni]);
          acc[mi][ni] = mfma16(a_l[mi], b_h[ni], acc[mi][ni]);
        }
    }
  }

  // epilogue: C/D layout col=lane&31, row=(reg&3)+8*(reg>>2)+4*(lane>>5)
#pragma unroll
  for (int mi = 0; mi < 2; mi++)
#pragma unroll
    for (int ni = 0; ni < 2; ni++) {
      int col = colTile + waveN * 64 + ni * 32 + l31;
#pragma unroll
      for (int reg = 0; reg < 16; reg++) {
        int rowIn = (reg & 3) + 8 * (reg >> 2) + 4 * lHalf;
        int rr = rowTile + waveM * 64 + mi * 32 + rowIn;
        coeffs[(size_t)rr * 1024 + col] = acc[mi][ni][reg];
      }
    }
}

// --------------------------------------------- gain search + quant/dequant --
// one WAVE per (b,f) frame; butterfly reduce; powf-free (sqrt/exp2/log2).
__global__ __launch_bounds__(256) void quantize(const float* __restrict__ cf,
                                                _Float16* __restrict__ dqh) {
  int wid = threadIdx.x >> 6, lane = threadIdx.x & 63;
  int bf = blockIdx.x * 4 + wid;     // 4 frames per 256-thread block
  int b = bf / F_, f = bf - b * F_;
  size_t base0 = ((size_t)(b * C_ + 0) * F_ + f) * 1024;
  size_t base1 = ((size_t)(b * C_ + 1) * F_ + f) * 1024;

  float x[32], ax75[32];
#pragma unroll
  for (int c = 0; c < 2; c++) {
    size_t bb = c ? base1 : base0;
#pragma unroll
    for (int j = 0; j < 4; j++) {
      float4 v = *(const float4*)(cf + bb + j * 256 + lane * 4);
      int o = c * 16 + j * 4;
      x[o + 0] = v.x; x[o + 1] = v.y; x[o + 2] = v.z; x[o + 3] = v.w;
    }
  }
#pragma unroll
  for (int u = 0; u < 32; u++) {
    float ax = fabsf(x[u]);
    float s  = sqrtf(ax);
    ax75[u]  = s * sqrtf(s);         // |x|^0.75
  }

  int lo = 0, hi = 120;
#pragma unroll
  for (int it = 0; it < 8; it++) {
    int mid = (lo + hi) >> 1;
    float inv = exp2f(-0.1875f * (float)mid);
    int s = 0;
#pragma unroll
    for (int u = 0; u < 32; u++) {
      float qm = rintf(ax75[u] * inv);
      int iq = (int)qm;
      s += (iq > 0) ? (33 - __clz(iq)) : 1;
    }
#pragma unroll
    for (int off = 1; off < 64; off <<= 1) s += __shfl_xor(s, off, 64);
    if (s >= TARGET_HI) lo = mid + 1; else hi = mid;   // uniform per wave
  }

  float scale = exp2f(0.25f * (float)hi);
  float rs    = exp2f(-0.25f * (float)hi);
#pragma unroll
  for (int c = 0; c < 2; c++) {
    size_t bb = c ? base1 : base0;
#pragma unroll
    for (int j = 0; j < 4; j++) {
      f16x4 o4;
#pragma unroll
      for (int e = 0; e < 4; e++) {
        int u = c * 16 + j * 4 + e;
        float ax  = fabsf(x[u]);
        float t   = ax * rs + 1e-9f;
        float s1  = sqrtf(t);
        float qs  = s1 * sqrtf(s1);              // (|x|/scale+eps)^0.75
        float q   = rintf(qs);
        float q43 = q * exp2f(__log2f(q) * (1.0f / 3.0f));  // q^(4/3)
        o4[e] = (_Float16)copysignf(q43 * scale, x[u]);
      }
      *(f16x4*)(dqh + bb + j * 256 + lane * 4) = o4;
    }
  }
}

// ------------------------------------------- inverse MDCT (f16 1-prod) -----
// GEMM only: td[r][n] = (2/M)*w[n]*sum_k dq[r,k]*Cm[n,k], stored as f16 into
// the DEAD coeff buffer (exact 92.3 MB fit). NO atomics (was 46M atomicAdds,
// est. ~150 us at ~128 f32-atomics/cycle chip-wide). OLA moved to own pass.
// td is audio-scale (+-2): f16 rounding adds ~1e-3 abs err, far below the
// 0.063 quantization-dominated absmax.
__global__ __launch_bounds__(256) void inv_gemm(const char* __restrict__ wsb,
                                                _Float16* __restrict__ tdh) {
  __shared__ __align__(16) _Float16 Ad[2][128][32];   // 2 x 8 KB
  __shared__ __align__(16) _Float16 Bd[2][256][32];   // 2 x 16 KB
  const _Float16* dqh = (const _Float16*)(wsb + OFF_DQ);
  const _Float16* cih = (const _Float16*)(wsb + OFF_CIH);
  const float*    wf  = (const float*)(wsb + OFF_WF);

  int tid = threadIdx.x;
  int lane = tid & 63, wid = tid >> 6;
  int l31 = lane & 31, lHalf = lane >> 5;
  int waveM = wid >> 1, waveN = wid & 1;
  int rowTile = blockIdx.x * 128, colTile = blockIdx.y * 256;

  // staging: lane l covers row l>>2, slot l&3; source octet (l&3)^((row>>1)&3)
  // (verified bijection: every 8 consecutive lanes cover all 32 banks)
  int srcRow = lane >> 2;
  int swz = ((lane & 3) ^ ((lane >> 3) & 3)) << 3;
  const _Float16* aS = dqh + (size_t)(rowTile + wid * 32 + srcRow) * 1024 + swz;
  const _Float16* bS = cih + (size_t)(colTile + wid * 64 + srcRow) * 1024 + swz;

  auto stage = [&](int kt, int buf) {
    gld_lds16(aS + kt,             &Ad[buf][wid * 32][0]);
    gld_lds16(aS + kt + 16 * 1024, &Ad[buf][wid * 32 + 16][0]);
#pragma unroll
    for (int j = 0; j < 4; j++)
      gld_lds16(bS + kt + (size_t)j * 16 * 1024, &Bd[buf][wid * 64 + j * 16][0]);
  };

  f32x16 acc[2][4];
#pragma unroll
  for (int i = 0; i < 2; i++)
#pragma unroll
    for (int j = 0; j < 4; j++)
#pragma unroll
      for (int e = 0; e < 16; e++) acc[i][j][e] = 0.f;

  stage(0, 0);
  asm volatile("s_waitcnt vmcnt(0)" ::: "memory");
  __syncthreads();

  int cur = 0;
  for (int kt = 0; kt < 1024; kt += 32) {
    if (kt + 32 < 1024) stage(kt + 32, cur ^ 1);
#pragma unroll
    for (int kc = 0; kc < 2; kc++) {
      int slot = ((kc * 2 + lHalf) ^ ((l31 >> 1) & 3)) << 4;
      const char* ar = (const char*)&Ad[cur][waveM * 64 + l31][0];
      const char* br = (const char*)&Bd[cur][waveN * 128 + l31][0];
      f16x8 a0 = *(const f16x8*)(ar + slot);
      f16x8 a1 = *(const f16x8*)(ar + 32 * 64 + slot);
      f16x8 b0 = *(const f16x8*)(br + slot);
      f16x8 b1 = *(const f16x8*)(br + 32 * 64 + slot);
      f16x8 b2 = *(const f16x8*)(br + 64 * 64 + slot);
      f16x8 b3 = *(const f16x8*)(br + 96 * 64 + slot);
      acc[0][0] = mfma16(a0, b0, acc[0][0]);
      acc[0][1] = mfma16(a0, b1, acc[0][1]);
      acc[0][2] = mfma16(a0, b2, acc[0][2]);
      acc[0][3] = mfma16(a0, b3, acc[0][3]);
      acc[1][0] = mfma16(a1, b0, acc[1][0]);
      acc[1][1] = mfma16(a1, b1, acc[1][1]);
      acc[1][2] = mfma16(a1, b2, acc[1][2]);
      acc[1][3] = mfma16(a1, b3, acc[1][3]);
    }
    asm volatile("s_waitcnt vmcnt(0)" ::: "memory");
    __syncthreads();
    cur ^= 1;
  }

  const float sc = 2.0f / 1024.0f;
#pragma unroll
  for (int mi = 0; mi < 2; mi++)
#pragma unroll
    for (int ni = 0; ni < 4; ni++) {
      int n = colTile + waveN * 128 + ni * 32 + l31;
      float wv = wf[n] * sc;
#pragma unroll
      for (int reg = 0; reg < 16; reg++) {
        int rowIn = (reg & 3) + 8 * (reg >> 2) + 4 * lHalf;
        int rr = rowTile + waveM * 64 + mi * 32 + rowIn;
        tdh[(size_t)rr * 2048 + n] = (_Float16)(acc[mi][ni][reg] * wv);
      }
    }
}

// --------------------------------------------------------- overlap-add ------
// out[bc][t] = td[bc, g+1][o] + td[bc, g][1024+o], g=t>>10, o=t&1023.
// Derivation: contribution n<1024 comes from frame f=g+1 (n=o); n>=1024 from
// f=g (n=1024+o). Both always valid: g in [0,1406] -> g+1 <= 1407 = F-1.
// Pure coalesced f16x8 reads + float4 stores; replaces memset + 46M atomics.
__global__ __launch_bounds__(256) void ola(const char* __restrict__ wsb,
                                           float* __restrict__ out) {
  const _Float16* tdh = (const _Float16*)(wsb + OFF_CF);
  int idx = blockIdx.x * 256 + threadIdx.x;
  size_t base = (size_t)idx * 8;           // global sample index (B*C*T total)
  int bc = (int)(base / T_);               // T_ % 8 == 0 -> no straddle
  int t  = (int)(base - (size_t)bc * T_);
  int g = t >> 10, o = t & 1023;           // o multiple of 8 -> no 1024-cross
  size_t r0 = (size_t)bc * F_ + g;
  f16x8 hi = *(const f16x8*)(tdh + (r0 + 1) * 2048 + o);
  f16x8 lo = *(const f16x8*)(tdh + r0 * 2048 + 1024 + o);
  float4 v0, v1;
  v0.x = (float)hi[0] + (float)lo[0];
  v0.y = (float)hi[1] + (float)lo[1];
  v0.z = (float)hi[2] + (float)lo[2];
  v0.w = (float)hi[3] + (float)lo[3];
  v1.x = (float)hi[4] + (float)lo[4];
  v1.y = (float)hi[5] + (float)lo[5];
  v1.z = (float)hi[6] + (float)lo[6];
  v1.w = (float)hi[7] + (float)lo[7];
  *(float4*)(out + base)     = v0;
  *(float4*)(out + base + 4) = v1;
}

// ------------------------------------------------------------------ launch --
extern "C" void kernel_launch(void* const* d_in, const int* in_sizes, int n_in,
                              void* d_out, int out_size, void* d_ws, size_t ws_size,
                              hipStream_t stream) {
  const float* audio = (const float*)d_in[0];
  float* out = (float*)d_out;
  char* wsb  = (char*)d_ws;
  float*    cf  = (float*)(wsb + OFF_CF);
  _Float16* dqh = (_Float16*)(wsb + OFF_DQ);
  _Float16* tdh = (_Float16*)(wsb + OFF_CF);   // cf is dead after quantize

  init_tables<<<(2097152 + 2048 + 255) / 256, 256, 0, stream>>>(wsb);
  fwd_mfma<<<dim3(R_ / 128, 1024 / 128), 256, 0, stream>>>(audio, wsb, cf);
  quantize<<<(B_ * F_) / 4, 256, 0, stream>>>(cf, dqh);
  inv_gemm<<<dim3(R_ / 128, 2048 / 256), 256, 0, stream>>>(wsb, tdh);
  ola<<<(B_ * C_ * T_) / (256 * 8), 256, 0, stream>>>(wsb, out);
}

// Round 6
// 695.708 us; speedup vs baseline: 1.4354x; 1.1472x over previous
//
#include <hip/hip_runtime.h>
#include <math.h>

// Problem constants (fixed by setup_inputs)
#define B_ 8
#define C_ 2
#define T_ 1440000
#define F_ 1408            // ceil((T+M)/M) with M=1024
#define R_ 22528           // B*C*F
#define TARGET_HI 2731     // bits > 2730.667  <=>  int bits >= 2731

// ws byte offsets
#define OFF_CFH 0ull                     // f16 [k=1024][n=2048] hi   (4 MiB)
#define OFF_CFL (4ull << 20)             // f16 [k=1024][n=2048] lo   (4 MiB)
#define OFF_CIH (8ull << 20)             // f16 folded cif [j=1024][k=1024] (2 MiB)
#define OFF_WF  (12ull << 20)            // f32 [2048]
#define OFF_CF  (13ull << 20)            // f32 [R_][1024] coeffs; REUSED as f16 tdu [R_][1024] (46 MB)
#define OFF_DQ  (OFF_CF + (size_t)R_ * 1024 * 4)   // f16 [R_][1024] (46 MB)

typedef _Float16 f16x8 __attribute__((ext_vector_type(8)));
typedef _Float16 f16x4 __attribute__((ext_vector_type(4)));
typedef float f32x16 __attribute__((ext_vector_type(16)));

__device__ inline f32x16 mfma16(f16x8 a, f16x8 b, f32x16 c) {
  return __builtin_amdgcn_mfma_f32_32x32x16_f16(a, b, c, 0, 0, 0);
}

// async global->LDS, 16B per lane. LDS dest = uniform base + lane*16.
__device__ inline void gld_lds16(const void* g, void* l) {
  __builtin_amdgcn_global_load_lds(
      (const __attribute__((address_space(1))) void*)g,
      (__attribute__((address_space(3))) void*)l, 16, 0, 0);
}

// ---------------------------------------------------------------- tables ----
// CRITICAL: reproduce the reference's float32 phase arithmetic EXACTLY
// (f32(pi/M) * f32(n+512.5) -> f32 round -> * f32(k+0.5) -> f32 round -> cos).
// IMDCT symmetry (exact in analytic math, ~2e-4 table-value deviation from
// f32-rounded phases): Cm[1023-n,k] = -Cm[n,k]; Cm[2047-m,k] = Cm[1024+m,k].
// => td has 1024 unique columns n_eff(j) = j (j<512) | 512+j (j>=512).
// cif[j][k] = Cm[n_eff(j)][k] is the folded inverse table.
__global__ __launch_bounds__(256) void init_tables(char* wsb) {
  _Float16* cfh = (_Float16*)(wsb + OFF_CFH);
  _Float16* cfl = (_Float16*)(wsb + OFF_CFL);
  _Float16* cif = (_Float16*)(wsb + OFF_CIH);
  float*    wf  = (float*)(wsb + OFF_WF);
  int idx = blockIdx.x * 256 + threadIdx.x;
  if (idx < 2097152) {
    int n = idx >> 10, k = idx & 1023;
    const float c0 = (float)(M_PI / 1024.0);
    float a  = (float)n + 0.5f + 512.0f;
    float t1 = c0 * a;
    float ph = t1 * ((float)k + 0.5f);
    float cm = (float)cos((double)ph);          // correctly-rounded cosf
    _Float16 h = (_Float16)cm;
    _Float16 l = (_Float16)(cm - (float)h);
    cfh[(size_t)k * 2048 + n] = h;
    cfl[(size_t)k * 2048 + n] = l;
    if (n < 512)                    cif[(size_t)n * 1024 + k] = h;
    else if (n >= 1024 && n < 1536) cif[(size_t)(n - 512) * 1024 + k] = h;
  } else if (idx < 2097152 + 2048) {
    int n = idx - 2097152;
    const float c1 = (float)(M_PI / 2048.0);
    float ph = c1 * ((float)n + 0.5f);
    wf[n] = (float)sin((double)ph);
  }
}

// ----------------------------------------------- forward MDCT (f16 3-prod) --
// UNCHANGED (round-0 structure, measured 388-398 us, MfmaUtil ~33%, 40 KB LDS,
// 4 blocks/CU). Bit-identical coeffs -> quantization flip-set preserved.
__global__ __launch_bounds__(256) void fwd_mfma(const float* __restrict__ audio,
                                                const char* __restrict__ wsb,
                                                float* __restrict__ coeffs) {
  __shared__ _Float16 Ah[128][40];
  __shared__ _Float16 Al[128][40];
  __shared__ _Float16 Bh[128][40];
  __shared__ _Float16 Bl[128][40];
  const _Float16* cfh = (const _Float16*)(wsb + OFF_CFH);
  const _Float16* cfl = (const _Float16*)(wsb + OFF_CFL);
  const float*    wf  = (const float*)(wsb + OFF_WF);

  int tid = threadIdx.x;
  int lane = tid & 63, wid = tid >> 6;
  int l31 = lane & 31, lHalf = lane >> 5;
  int waveM = wid >> 1, waveN = wid & 1;
  int rowTile = blockIdx.x * 128, colTile = blockIdx.y * 128;

  int sRow = tid >> 1;
  int sSeg = (tid & 1) << 4;
  int r = rowTile + sRow, bc = r / F_, f = r - bc * F_;
  const float* __restrict__ aud = audio + (size_t)bc * T_;
  int tBase = (f << 10) - 1024 + sSeg;
  const _Float16* bhp = cfh + (size_t)(colTile + sRow) * 2048 + sSeg;
  const _Float16* blp = cfl + (size_t)(colTile + sRow) * 2048 + sSeg;

  f32x16 acc[2][2];
#pragma unroll
  for (int i = 0; i < 2; i++)
#pragma unroll
    for (int j = 0; j < 2; j++)
#pragma unroll
      for (int e = 0; e < 16; e++) acc[i][j][e] = 0.f;

  for (int kt = 0; kt < 2048; kt += 32) {
    float av[16];
    int t0 = tBase + kt;
    if (t0 >= 0 && t0 + 16 <= T_) {
#pragma unroll
      for (int q = 0; q < 4; q++) {
        float4 x = *(const float4*)(aud + t0 + q * 4);
        av[q * 4 + 0] = x.x; av[q * 4 + 1] = x.y;
        av[q * 4 + 2] = x.z; av[q * 4 + 3] = x.w;
      }
    } else {
#pragma unroll
      for (int i = 0; i < 16; i++) {
        int t = t0 + i;
        av[i] = (t >= 0 && t < T_) ? aud[t] : 0.f;
      }
    }
    f16x8 vh[2], vl[2];
#pragma unroll
    for (int i = 0; i < 16; i++) {
      float v = av[i] * wf[kt + sSeg + i];
      _Float16 h = (_Float16)v;
      vh[i >> 3][i & 7] = h;
      vl[i >> 3][i & 7] = (_Float16)(v - (float)h);
    }
    float4 tb0 = *(const float4*)(bhp + kt);
    float4 tb1 = *(const float4*)(bhp + kt + 8);
    float4 tl0 = *(const float4*)(blp + kt);
    float4 tl1 = *(const float4*)(blp + kt + 8);

    __syncthreads();
    *(f16x8*)&Ah[sRow][sSeg]     = vh[0];
    *(f16x8*)&Ah[sRow][sSeg + 8] = vh[1];
    *(f16x8*)&Al[sRow][sSeg]     = vl[0];
    *(f16x8*)&Al[sRow][sSeg + 8] = vl[1];
    *(float4*)&Bh[sRow][sSeg]     = tb0;
    *(float4*)&Bh[sRow][sSeg + 8] = tb1;
    *(float4*)&Bl[sRow][sSeg]     = tl0;
    *(float4*)&Bl[sRow][sSeg + 8] = tl1;
    __syncthreads();

#pragma unroll
    for (int kc = 0; kc < 2; kc++) {
      int ko = kc * 16 + lHalf * 8;
      f16x8 a_h[2], a_l[2], b_h[2], b_l[2];
#pragma unroll
      for (int mi = 0; mi < 2; mi++) {
        a_h[mi] = *(const f16x8*)&Ah[waveM * 64 + mi * 32 + l31][ko];
        a_l[mi] = *(const f16x8*)&Al[waveM * 64 + mi * 32 + l31][ko];
      }
#pragma unroll
      for (int ni = 0; ni < 2; ni++) {
        b_h[ni] = *(const f16x8*)&Bh[waveN * 64 + ni * 32 + l31][ko];
        b_l[ni] = *(const f16x8*)&Bl[waveN * 64 + ni * 32 + l31][ko];
      }
#pragma unroll
      for (int mi = 0; mi < 2; mi++)
#pragma unroll
        for (int ni = 0; ni < 2; ni++) {
          acc[mi][ni] = mfma16(a_h[mi], b_h[ni], acc[mi][ni]);
          acc[mi][ni] = mfma16(a_h[mi], b_l[ni], acc[mi][ni]);
          acc[mi][ni] = mfma16(a_l[mi], b_h[ni], acc[mi][ni]);
        }
    }
  }

  // epilogue: C/D layout col=lane&31, row=(reg&3)+8*(reg>>2)+4*(lane>>5)
#pragma unroll
  for (int mi = 0; mi < 2; mi++)
#pragma unroll
    for (int ni = 0; ni < 2; ni++) {
      int col = colTile + waveN * 64 + ni * 32 + l31;
#pragma unroll
      for (int reg = 0; reg < 16; reg++) {
        int rowIn = (reg & 3) + 8 * (reg >> 2) + 4 * lHalf;
        int rr = rowTile + waveM * 64 + mi * 32 + rowIn;
        coeffs[(size_t)rr * 1024 + col] = acc[mi][ni][reg];
      }
    }
}

// --------------------------------------------- gain search + quant/dequant --
// one WAVE per (b,f) frame; butterfly reduce; powf-free (sqrt/exp2/log2).
__global__ __launch_bounds__(256) void quantize(const float* __restrict__ cf,
                                                _Float16* __restrict__ dqh) {
  int wid = threadIdx.x >> 6, lane = threadIdx.x & 63;
  int bf = blockIdx.x * 4 + wid;     // 4 frames per 256-thread block
  int b = bf / F_, f = bf - b * F_;
  size_t base0 = ((size_t)(b * C_ + 0) * F_ + f) * 1024;
  size_t base1 = ((size_t)(b * C_ + 1) * F_ + f) * 1024;

  float x[32], ax75[32];
#pragma unroll
  for (int c = 0; c < 2; c++) {
    size_t bb = c ? base1 : base0;
#pragma unroll
    for (int j = 0; j < 4; j++) {
      float4 v = *(const float4*)(cf + bb + j * 256 + lane * 4);
      int o = c * 16 + j * 4;
      x[o + 0] = v.x; x[o + 1] = v.y; x[o + 2] = v.z; x[o + 3] = v.w;
    }
  }
#pragma unroll
  for (int u = 0; u < 32; u++) {
    float ax = fabsf(x[u]);
    float s  = sqrtf(ax);
    ax75[u]  = s * sqrtf(s);         // |x|^0.75
  }

  int lo = 0, hi = 120;
#pragma unroll
  for (int it = 0; it < 8; it++) {
    int mid = (lo + hi) >> 1;
    float inv = exp2f(-0.1875f * (float)mid);
    int s = 0;
#pragma unroll
    for (int u = 0; u < 32; u++) {
      float qm = rintf(ax75[u] * inv);
      int iq = (int)qm;
      s += (iq > 0) ? (33 - __clz(iq)) : 1;
    }
#pragma unroll
    for (int off = 1; off < 64; off <<= 1) s += __shfl_xor(s, off, 64);
    if (s >= TARGET_HI) lo = mid + 1; else hi = mid;   // uniform per wave
  }

  float scale = exp2f(0.25f * (float)hi);
  float rs    = exp2f(-0.25f * (float)hi);
#pragma unroll
  for (int c = 0; c < 2; c++) {
    size_t bb = c ? base1 : base0;
#pragma unroll
    for (int j = 0; j < 4; j++) {
      f16x4 o4;
#pragma unroll
      for (int e = 0; e < 4; e++) {
        int u = c * 16 + j * 4 + e;
        float ax  = fabsf(x[u]);
        float t   = ax * rs + 1e-9f;
        float s1  = sqrtf(t);
        float qs  = s1 * sqrtf(s1);              // (|x|/scale+eps)^0.75
        float q   = rintf(qs);
        float q43 = q * exp2f(__log2f(q) * (1.0f / 3.0f));  // q^(4/3)
        o4[e] = (_Float16)copysignf(q43 * scale, x[u]);
      }
      *(f16x4*)(dqh + bb + j * 256 + lane * 4) = o4;
    }
  }
}

// ------------------------------------- FOLDED inverse MDCT (f16 1-prod) ----
// tdu[r][j] = sc * sum_k dq[r,k]*cif[j][k], j in [0,1024) — HALF the output
// columns of the full IMDCT (symmetry expansion + windowing moved to ola).
// Same proven 2-phase body as round 5; grid colTiles 8 -> 4 (work halves).
__global__ __launch_bounds__(256) void inv_gemm(const char* __restrict__ wsb,
                                                _Float16* __restrict__ tdh) {
  __shared__ __align__(16) _Float16 Ad[2][128][32];   // 2 x 8 KB
  __shared__ __align__(16) _Float16 Bd[2][256][32];   // 2 x 16 KB
  const _Float16* dqh = (const _Float16*)(wsb + OFF_DQ);
  const _Float16* cif = (const _Float16*)(wsb + OFF_CIH);

  int tid = threadIdx.x;
  int lane = tid & 63, wid = tid >> 6;
  int l31 = lane & 31, lHalf = lane >> 5;
  int waveM = wid >> 1, waveN = wid & 1;
  int rowTile = blockIdx.x * 128, colTile = blockIdx.y * 256;

  // staging: lane l covers row l>>2, slot l&3; source octet (l&3)^((row>>1)&3)
  // (verified bijection: every 8 consecutive lanes cover all 32 banks)
  int srcRow = lane >> 2;
  int swz = ((lane & 3) ^ ((lane >> 3) & 3)) << 3;
  const _Float16* aS = dqh + (size_t)(rowTile + wid * 32 + srcRow) * 1024 + swz;
  const _Float16* bS = cif + (size_t)(colTile + wid * 64 + srcRow) * 1024 + swz;

  auto stage = [&](int kt, int buf) {
    gld_lds16(aS + kt,             &Ad[buf][wid * 32][0]);
    gld_lds16(aS + kt + 16 * 1024, &Ad[buf][wid * 32 + 16][0]);
#pragma unroll
    for (int j = 0; j < 4; j++)
      gld_lds16(bS + kt + (size_t)j * 16 * 1024, &Bd[buf][wid * 64 + j * 16][0]);
  };

  f32x16 acc[2][4];
#pragma unroll
  for (int i = 0; i < 2; i++)
#pragma unroll
    for (int j = 0; j < 4; j++)
#pragma unroll
      for (int e = 0; e < 16; e++) acc[i][j][e] = 0.f;

  stage(0, 0);
  asm volatile("s_waitcnt vmcnt(0)" ::: "memory");
  __syncthreads();

  int cur = 0;
  for (int kt = 0; kt < 1024; kt += 32) {
    if (kt + 32 < 1024) stage(kt + 32, cur ^ 1);
#pragma unroll
    for (int kc = 0; kc < 2; kc++) {
      int slot = ((kc * 2 + lHalf) ^ ((l31 >> 1) & 3)) << 4;
      const char* ar = (const char*)&Ad[cur][waveM * 64 + l31][0];
      const char* br = (const char*)&Bd[cur][waveN * 128 + l31][0];
      f16x8 a0 = *(const f16x8*)(ar + slot);
      f16x8 a1 = *(const f16x8*)(ar + 32 * 64 + slot);
      f16x8 b0 = *(const f16x8*)(br + slot);
      f16x8 b1 = *(const f16x8*)(br + 32 * 64 + slot);
      f16x8 b2 = *(const f16x8*)(br + 64 * 64 + slot);
      f16x8 b3 = *(const f16x8*)(br + 96 * 64 + slot);
      acc[0][0] = mfma16(a0, b0, acc[0][0]);
      acc[0][1] = mfma16(a0, b1, acc[0][1]);
      acc[0][2] = mfma16(a0, b2, acc[0][2]);
      acc[0][3] = mfma16(a0, b3, acc[0][3]);
      acc[1][0] = mfma16(a1, b0, acc[1][0]);
      acc[1][1] = mfma16(a1, b1, acc[1][1]);
      acc[1][2] = mfma16(a1, b2, acc[1][2]);
      acc[1][3] = mfma16(a1, b3, acc[1][3]);
    }
    asm volatile("s_waitcnt vmcnt(0)" ::: "memory");
    __syncthreads();
    cur ^= 1;
  }

  const float sc = 2.0f / 1024.0f;
#pragma unroll
  for (int mi = 0; mi < 2; mi++)
#pragma unroll
    for (int ni = 0; ni < 4; ni++) {
      int n = colTile + waveN * 128 + ni * 32 + l31;   // = j in [0,1024)
#pragma unroll
      for (int reg = 0; reg < 16; reg++) {
        int rowIn = (reg & 3) + 8 * (reg >> 2) + 4 * lHalf;
        int rr = rowTile + waveM * 64 + mi * 32 + rowIn;
        tdh[(size_t)rr * 1024 + n] = (_Float16)(acc[mi][ni][reg] * sc);
      }
    }
}

// --------------------------------------------- overlap-add + sym expand -----
// out[bc][t] = w[o]*td[g+1][o] + w[1024+o]*td[g][1024+o], g=t>>10, o=t&1023,
// with td expanded from tdu: td[n] = tdu[n] (n<512) | -tdu[1023-n] (n<1024)
//                          | tdu[n-512] (n<1536) | tdu[3071-n] (n<2048).
// Each wave covers exactly 512 consecutive samples -> o<512 branch is
// wave-uniform. Reversed reads stay aligned f16x8 (reverse in-register).
__global__ __launch_bounds__(256) void ola(const char* __restrict__ wsb,
                                           float* __restrict__ out) {
  const _Float16* tdu = (const _Float16*)(wsb + OFF_CF);
  const float*    wf  = (const float*)(wsb + OFF_WF);
  int idx = blockIdx.x * 256 + threadIdx.x;
  size_t base = (size_t)idx * 8;           // global sample index (B*C*T total)
  int bc = (int)(base / T_);               // T_ % 8 == 0 -> no straddle
  int t  = (int)(base - (size_t)bc * T_);
  int g = t >> 10, o = t & 1023;           // o multiple of 8
  size_t r0 = (size_t)bc * F_ + g;         // g+1 <= 1407 always valid
  float w1[8], w2[8];
  *(float4*)&w1[0] = *(const float4*)(wf + o);
  *(float4*)&w1[4] = *(const float4*)(wf + o + 4);
  *(float4*)&w2[0] = *(const float4*)(wf + 1024 + o);
  *(float4*)&w2[4] = *(const float4*)(wf + 1024 + o + 4);
  const float sc = 1.0f;                   // 2/M already applied in inv_gemm
  float rv[8];
  if (o < 512) {
    f16x8 a = *(const f16x8*)(tdu + (r0 + 1) * 1024 + o);          // td[g+1][o]
    f16x8 b = *(const f16x8*)(tdu + r0 * 1024 + 512 + o);          // td[g][1024+o]
#pragma unroll
    for (int i = 0; i < 8; i++)
      rv[i] = (w1[i] * (float)a[i] + w2[i] * (float)b[i]) * sc;
  } else {
    f16x8 a = *(const f16x8*)(tdu + (r0 + 1) * 1024 + (1016 - o)); // rev: 1023-(o+i)
    f16x8 b = *(const f16x8*)(tdu + r0 * 1024 + (1528 - o));       // rev: 1535-(o+i)
#pragma unroll
    for (int i = 0; i < 8; i++)
      rv[i] = (w2[i] * (float)b[7 - i] - w1[i] * (float)a[7 - i]) * sc;
  }
  float4 v0, v1;
  v0.x = rv[0]; v0.y = rv[1]; v0.z = rv[2]; v0.w = rv[3];
  v1.x = rv[4]; v1.y = rv[5]; v1.z = rv[6]; v1.w = rv[7];
  *(float4*)(out + base)     = v0;
  *(float4*)(out + base + 4) = v1;
}

// ------------------------------------------------------------------ launch --
extern "C" void kernel_launch(void* const* d_in, const int* in_sizes, int n_in,
                              void* d_out, int out_size, void* d_ws, size_t ws_size,
                              hipStream_t stream) {
  const float* audio = (const float*)d_in[0];
  float* out = (float*)d_out;
  char* wsb  = (char*)d_ws;
  float*    cf  = (float*)(wsb + OFF_CF);
  _Float16* dqh = (_Float16*)(wsb + OFF_DQ);
  _Float16* tdh = (_Float16*)(wsb + OFF_CF);   // cf is dead after quantize

  init_tables<<<(2097152 + 2048 + 255) / 256, 256, 0, stream>>>(wsb);
  fwd_mfma<<<dim3(R_ / 128, 1024 / 128), 256, 0, stream>>>(audio, wsb, cf);
  quantize<<<(B_ * F_) / 4, 256, 0, stream>>>(cf, dqh);
  inv_gemm<<<dim3(R_ / 128, 1024 / 256), 256, 0, stream>>>(wsb, tdh);
  ola<<<(B_ * C_ * T_) / (256 * 8), 256, 0, stream>>>(wsb, out);
}

// Round 9
// 671.859 us; speedup vs baseline: 1.4863x; 1.0355x over previous
//
#include <hip/hip_runtime.h>
#include <math.h>

// Problem constants (fixed by setup_inputs)
#define B_ 8
#define C_ 2
#define T_ 1440000
#define F_ 1408            // ceil((T+M)/M) with M=1024
#define R_ 22528           // B*C*F
#define TARGET_HI 2731     // bits > 2730.667  <=>  int bits >= 2731

// ws byte offsets
#define OFF_CFH 0ull                     // f16 [k=1024][n=2048] hi   (4 MiB)
#define OFF_CFL (4ull << 20)             // f16 [k=1024][n=2048] lo   (4 MiB)
#define OFF_CIH (8ull << 20)             // f16 folded cif [j=1024][k=1024] (2 MiB)
#define OFF_WF  (12ull << 20)            // f32 [2048]
#define OFF_CF  (13ull << 20)            // f32 [R_][1024] coeffs; REUSED as f16 tdu [R_][1024]
#define OFF_DQ  (OFF_CF + (size_t)R_ * 1024 * 4)   // f16 [R_][1024] (46 MB)

typedef _Float16 f16x8 __attribute__((ext_vector_type(8)));
typedef _Float16 f16x4 __attribute__((ext_vector_type(4)));
typedef float f32x16 __attribute__((ext_vector_type(16)));

__device__ inline f32x16 mfma16(f16x8 a, f16x8 b, f32x16 c) {
  return __builtin_amdgcn_mfma_f32_32x32x16_f16(a, b, c, 0, 0, 0);
}

// async global->LDS, 16B per lane. LDS dest = uniform base + lane*16.
__device__ inline void gld_lds16(const void* g, void* l) {
  __builtin_amdgcn_global_load_lds(
      (const __attribute__((address_space(1))) void*)g,
      (__attribute__((address_space(3))) void*)l, 16, 0, 0);
}

// NUMERICS CONTRACT (hardened by round-8 failure, absmax 1.49 > thr 0.0775):
// everything UPSTREAM of the quantizer (fwd tables, fwd GEMM order) must stay
// bit-exact to the round-0 lineage (absmax canary 0.06347656, thr headroom
// only 22%). Downstream (post-quantize) f16/symmetry approximations are
// measured-safe (round 6: zero absmax movement). The fwd symmetry fold is
// permanently dead: ~8e-4 table-representative deviation flips gain decisions.

// ---------------------------------------------------------------- tables ----
// CRITICAL: reproduce the reference's float32 phase arithmetic EXACTLY
// (f32(pi/M) * f32(n+512.5) -> f32 round -> * f32(k+0.5) -> f32 round -> cos).
// IMDCT symmetry (downstream-only): Cm[1023-n,k]=-Cm[n,k]; Cm[2047-m,k]=
// Cm[1024+m,k] => cif[j][k]=Cm[n_eff(j)][k], n_eff(j)= j (j<512) | 512+j.
__global__ __launch_bounds__(256) void init_tables(char* wsb) {
  _Float16* cfh = (_Float16*)(wsb + OFF_CFH);
  _Float16* cfl = (_Float16*)(wsb + OFF_CFL);
  _Float16* cif = (_Float16*)(wsb + OFF_CIH);
  float*    wf  = (float*)(wsb + OFF_WF);
  int idx = blockIdx.x * 256 + threadIdx.x;
  if (idx < 2097152) {
    int n = idx >> 10, k = idx & 1023;
    const float c0 = (float)(M_PI / 1024.0);
    float a  = (float)n + 0.5f + 512.0f;
    float t1 = c0 * a;
    float ph = t1 * ((float)k + 0.5f);
    float cm = (float)cos((double)ph);          // correctly-rounded cosf
    _Float16 h = (_Float16)cm;
    _Float16 l = (_Float16)(cm - (float)h);
    cfh[(size_t)k * 2048 + n] = h;
    cfl[(size_t)k * 2048 + n] = l;
    if (n < 512)                    cif[(size_t)n * 1024 + k] = h;
    else if (n >= 1024 && n < 1536) cif[(size_t)(n - 512) * 1024 + k] = h;
  } else if (idx < 2097152 + 2048) {
    int n = idx - 2097152;
    const float c1 = (float)(M_PI / 2048.0);
    float ph = c1 * ((float)n + 0.5f);
    wf[n] = (float)sin((double)ph);
  }
}

// ----------------------------------------------- forward MDCT (f16 3-prod) --
// Round-0 structure (proven 388-398 us, MfmaUtil ~33%, 40 KB LDS, 4 blk/CU).
// NEW (arithmetic-free): 1D grid, colTile-FAST ordering + XCD chunk swizzle —
// the 8 blocks sharing a rowTile's audio (~0.5 MB) run on the SAME XCD's L2.
// Old (176,8) grid had rowTile fastest: audio (92 MB) re-streamed 8x
// (FETCH_SIZE 545 MB measured). Every computed value is bit-identical.
__global__ __launch_bounds__(256) void fwd_mfma(const float* __restrict__ audio,
                                                const char* __restrict__ wsb,
                                                float* __restrict__ coeffs) {
  __shared__ _Float16 Ah[128][40];
  __shared__ _Float16 Al[128][40];
  __shared__ _Float16 Bh[128][40];
  __shared__ _Float16 Bl[128][40];
  const _Float16* cfh = (const _Float16*)(wsb + OFF_CFH);
  const _Float16* cfl = (const _Float16*)(wsb + OFF_CFL);
  const float*    wf  = (const float*)(wsb + OFF_WF);

  int tid = threadIdx.x;
  int lane = tid & 63, wid = tid >> 6;
  int l31 = lane & 31, lHalf = lane >> 5;
  int waveM = wid >> 1, waveN = wid & 1;

  // nwg=1408: hw round-robins XCDs; wgid=(hw&7)*176+(hw>>3) gives XCD x the
  // contiguous chunk [x*176,(x+1)*176) -> colTile-fast neighbors co-resident.
  int hw = blockIdx.x;
  int wgid = (hw & 7) * 176 + (hw >> 3);
  int rowTile = (wgid >> 3) * 128;
  int colTile = (wgid & 7) * 128;

  int sRow = tid >> 1;
  int sSeg = (tid & 1) << 4;
  int r = rowTile + sRow, bc = r / F_, f = r - bc * F_;
  const float* __restrict__ aud = audio + (size_t)bc * T_;
  int tBase = (f << 10) - 1024 + sSeg;
  const _Float16* bhp = cfh + (size_t)(colTile + sRow) * 2048 + sSeg;
  const _Float16* blp = cfl + (size_t)(colTile + sRow) * 2048 + sSeg;

  f32x16 acc[2][2];
#pragma unroll
  for (int i = 0; i < 2; i++)
#pragma unroll
    for (int j = 0; j < 2; j++)
#pragma unroll
      for (int e = 0; e < 16; e++) acc[i][j][e] = 0.f;

  for (int kt = 0; kt < 2048; kt += 32) {
    float av[16];
    int t0 = tBase + kt;
    if (t0 >= 0 && t0 + 16 <= T_) {
#pragma unroll
      for (int q = 0; q < 4; q++) {
        float4 x = *(const float4*)(aud + t0 + q * 4);
        av[q * 4 + 0] = x.x; av[q * 4 + 1] = x.y;
        av[q * 4 + 2] = x.z; av[q * 4 + 3] = x.w;
      }
    } else {
#pragma unroll
      for (int i = 0; i < 16; i++) {
        int t = t0 + i;
        av[i] = (t >= 0 && t < T_) ? aud[t] : 0.f;
      }
    }
    f16x8 vh[2], vl[2];
#pragma unroll
    for (int i = 0; i < 16; i++) {
      float v = av[i] * wf[kt + sSeg + i];
      _Float16 h = (_Float16)v;
      vh[i >> 3][i & 7] = h;
      vl[i >> 3][i & 7] = (_Float16)(v - (float)h);
    }
    float4 tb0 = *(const float4*)(bhp + kt);
    float4 tb1 = *(const float4*)(bhp + kt + 8);
    float4 tl0 = *(const float4*)(blp + kt);
    float4 tl1 = *(const float4*)(blp + kt + 8);

    __syncthreads();
    *(f16x8*)&Ah[sRow][sSeg]     = vh[0];
    *(f16x8*)&Ah[sRow][sSeg + 8] = vh[1];
    *(f16x8*)&Al[sRow][sSeg]     = vl[0];
    *(f16x8*)&Al[sRow][sSeg + 8] = vl[1];
    *(float4*)&Bh[sRow][sSeg]     = tb0;
    *(float4*)&Bh[sRow][sSeg + 8] = tb1;
    *(float4*)&Bl[sRow][sSeg]     = tl0;
    *(float4*)&Bl[sRow][sSeg + 8] = tl1;
    __syncthreads();

#pragma unroll
    for (int kc = 0; kc < 2; kc++) {
      int ko = kc * 16 + lHalf * 8;
      f16x8 a_h[2], a_l[2], b_h[2], b_l[2];
#pragma unroll
      for (int mi = 0; mi < 2; mi++) {
        a_h[mi] = *(const f16x8*)&Ah[waveM * 64 + mi * 32 + l31][ko];
        a_l[mi] = *(const f16x8*)&Al[waveM * 64 + mi * 32 + l31][ko];
      }
#pragma unroll
      for (int ni = 0; ni < 2; ni++) {
        b_h[ni] = *(const f16x8*)&Bh[waveN * 64 + ni * 32 + l31][ko];
        b_l[ni] = *(const f16x8*)&Bl[waveN * 64 + ni * 32 + l31][ko];
      }
#pragma unroll
      for (int mi = 0; mi < 2; mi++)
#pragma unroll
        for (int ni = 0; ni < 2; ni++) {
          acc[mi][ni] = mfma16(a_h[mi], b_h[ni], acc[mi][ni]);
          acc[mi][ni] = mfma16(a_h[mi], b_l[ni], acc[mi][ni]);
          acc[mi][ni] = mfma16(a_l[mi], b_h[ni], acc[mi][ni]);
        }
    }
  }

  // epilogue: C/D layout col=lane&31, row=(reg&3)+8*(reg>>2)+4*(lane>>5)
#pragma unroll
  for (int mi = 0; mi < 2; mi++)
#pragma unroll
    for (int ni = 0; ni < 2; ni++) {
      int col = colTile + waveN * 64 + ni * 32 + l31;
#pragma unroll
      for (int reg = 0; reg < 16; reg++) {
        int rowIn = (reg & 3) + 8 * (reg >> 2) + 4 * lHalf;
        int rr = rowTile + waveM * 64 + mi * 32 + rowIn;
        coeffs[(size_t)rr * 1024 + col] = acc[mi][ni][reg];
      }
    }
}

// --------------------------------------------- gain search + quant/dequant --
// one WAVE per (b,f) frame; butterfly reduce; powf-free (sqrt/exp2/log2).
__global__ __launch_bounds__(256) void quantize(const float* __restrict__ cf,
                                                _Float16* __restrict__ dqh) {
  int wid = threadIdx.x >> 6, lane = threadIdx.x & 63;
  int bf = blockIdx.x * 4 + wid;     // 4 frames per 256-thread block
  int b = bf / F_, f = bf - b * F_;
  size_t base0 = ((size_t)(b * C_ + 0) * F_ + f) * 1024;
  size_t base1 = ((size_t)(b * C_ + 1) * F_ + f) * 1024;

  float x[32], ax75[32];
#pragma unroll
  for (int c = 0; c < 2; c++) {
    size_t bb = c ? base1 : base0;
#pragma unroll
    for (int j = 0; j < 4; j++) {
      float4 v = *(const float4*)(cf + bb + j * 256 + lane * 4);
      int o = c * 16 + j * 4;
      x[o + 0] = v.x; x[o + 1] = v.y; x[o + 2] = v.z; x[o + 3] = v.w;
    }
  }
#pragma unroll
  for (int u = 0; u < 32; u++) {
    float ax = fabsf(x[u]);
    float s  = sqrtf(ax);
    ax75[u]  = s * sqrtf(s);         // |x|^0.75
  }

  int lo = 0, hi = 120;
#pragma unroll
  for (int it = 0; it < 8; it++) {
    int mid = (lo + hi) >> 1;
    float inv = exp2f(-0.1875f * (float)mid);
    int s = 0;
#pragma unroll
    for (int u = 0; u < 32; u++) {
      float qm = rintf(ax75[u] * inv);
      int iq = (int)qm;
      s += (iq > 0) ? (33 - __clz(iq)) : 1;
    }
#pragma unroll
    for (int off = 1; off < 64; off <<= 1) s += __shfl_xor(s, off, 64);
    if (s >= TARGET_HI) lo = mid + 1; else hi = mid;   // uniform per wave
  }

  float scale = exp2f(0.25f * (float)hi);
  float rs    = exp2f(-0.25f * (float)hi);
#pragma unroll
  for (int c = 0; c < 2; c++) {
    size_t bb = c ? base1 : base0;
#pragma unroll
    for (int j = 0; j < 4; j++) {
      f16x4 o4;
#pragma unroll
      for (int e = 0; e < 4; e++) {
        int u = c * 16 + j * 4 + e;
        float ax  = fabsf(x[u]);
        float t   = ax * rs + 1e-9f;
        float s1  = sqrtf(t);
        float qs  = s1 * sqrtf(s1);              // (|x|/scale+eps)^0.75
        float q   = rintf(qs);
        float q43 = q * exp2f(__log2f(q) * (1.0f / 3.0f));  // q^(4/3)
        o4[e] = (_Float16)copysignf(q43 * scale, x[u]);
      }
      *(f16x4*)(dqh + bb + j * 256 + lane * 4) = o4;
    }
  }
}

// ------------------------------------- FOLDED inverse MDCT (f16 1-prod) ----
// tdu[r][j] = sc * sum_k dq[r,k]*cif[j][k], j in [0,1024). Proven 2-phase body.
// NEW: 1D grid, colTile-fast + XCD chunk swizzle (dqh rows shared on-XCD).
__global__ __launch_bounds__(256) void inv_gemm(const char* __restrict__ wsb,
                                                _Float16* __restrict__ tdh) {
  __shared__ __align__(16) _Float16 Ad[2][128][32];   // 2 x 8 KB
  __shared__ __align__(16) _Float16 Bd[2][256][32];   // 2 x 16 KB
  const _Float16* dqh = (const _Float16*)(wsb + OFF_DQ);
  const _Float16* cif = (const _Float16*)(wsb + OFF_CIH);

  int tid = threadIdx.x;
  int lane = tid & 63, wid = tid >> 6;
  int l31 = lane & 31, lHalf = lane >> 5;
  int waveM = wid >> 1, waveN = wid & 1;

  // nwg=704: wgid=(hw&7)*88+(hw>>3); colTile fast (4 per rowTile).
  int hw = blockIdx.x;
  int wgid = (hw & 7) * 88 + (hw >> 3);
  int rowTile = (wgid >> 2) * 128;
  int colTile = (wgid & 3) * 256;

  // staging: lane l covers row l>>2, slot l&3; source octet (l&3)^((row>>1)&3)
  int srcRow = lane >> 2;
  int swz = ((lane & 3) ^ ((lane >> 3) & 3)) << 3;
  const _Float16* aS = dqh + (size_t)(rowTile + wid * 32 + srcRow) * 1024 + swz;
  const _Float16* bS = cif + (size_t)(colTile + wid * 64 + srcRow) * 1024 + swz;

  auto stage = [&](int kt, int buf) {
    gld_lds16(aS + kt,             &Ad[buf][wid * 32][0]);
    gld_lds16(aS + kt + 16 * 1024, &Ad[buf][wid * 32 + 16][0]);
#pragma unroll
    for (int j = 0; j < 4; j++)
      gld_lds16(bS + kt + (size_t)j * 16 * 1024, &Bd[buf][wid * 64 + j * 16][0]);
  };

  f32x16 acc[2][4];
#pragma unroll
  for (int i = 0; i < 2; i++)
#pragma unroll
    for (int j = 0; j < 4; j++)
#pragma unroll
      for (int e = 0; e < 16; e++) acc[i][j][e] = 0.f;

  stage(0, 0);
  asm volatile("s_waitcnt vmcnt(0)" ::: "memory");
  __syncthreads();

  int cur = 0;
  for (int kt = 0; kt < 1024; kt += 32) {
    if (kt + 32 < 1024) stage(kt + 32, cur ^ 1);
#pragma unroll
    for (int kc = 0; kc < 2; kc++) {
      int slot = ((kc * 2 + lHalf) ^ ((l31 >> 1) & 3)) << 4;
      const char* ar = (const char*)&Ad[cur][waveM * 64 + l31][0];
      const char* br = (const char*)&Bd[cur][waveN * 128 + l31][0];
      f16x8 a0 = *(const f16x8*)(ar + slot);
      f16x8 a1 = *(const f16x8*)(ar + 32 * 64 + slot);
      f16x8 b0 = *(const f16x8*)(br + slot);
      f16x8 b1 = *(const f16x8*)(br + 32 * 64 + slot);
      f16x8 b2 = *(const f16x8*)(br + 64 * 64 + slot);
      f16x8 b3 = *(const f16x8*)(br + 96 * 64 + slot);
      acc[0][0] = mfma16(a0, b0, acc[0][0]);
      acc[0][1] = mfma16(a0, b1, acc[0][1]);
      acc[0][2] = mfma16(a0, b2, acc[0][2]);
      acc[0][3] = mfma16(a0, b3, acc[0][3]);
      acc[1][0] = mfma16(a1, b0, acc[1][0]);
      acc[1][1] = mfma16(a1, b1, acc[1][1]);
      acc[1][2] = mfma16(a1, b2, acc[1][2]);
      acc[1][3] = mfma16(a1, b3, acc[1][3]);
    }
    asm volatile("s_waitcnt vmcnt(0)" ::: "memory");
    __syncthreads();
    cur ^= 1;
  }

  const float sc = 2.0f / 1024.0f;
#pragma unroll
  for (int mi = 0; mi < 2; mi++)
#pragma unroll
    for (int ni = 0; ni < 4; ni++) {
      int n = colTile + waveN * 128 + ni * 32 + l31;   // = j in [0,1024)
#pragma unroll
      for (int reg = 0; reg < 16; reg++) {
        int rowIn = (reg & 3) + 8 * (reg >> 2) + 4 * lHalf;
        int rr = rowTile + waveM * 64 + mi * 32 + rowIn;
        tdh[(size_t)rr * 1024 + n] = (_Float16)(acc[mi][ni][reg] * sc);
      }
    }
}

// --------------------------------------------- overlap-add + sym expand -----
// out[bc][t] = w[o]*td[g+1][o] + w[1024+o]*td[g][1024+o], td expanded from tdu.
__global__ __launch_bounds__(256) void ola(const char* __restrict__ wsb,
                                           float* __restrict__ out) {
  const _Float16* tdu = (const _Float16*)(wsb + OFF_CF);
  const float*    wf  = (const float*)(wsb + OFF_WF);
  int idx = blockIdx.x * 256 + threadIdx.x;
  size_t base = (size_t)idx * 8;           // global sample index (B*C*T total)
  int bc = (int)(base / T_);               // T_ % 8 == 0 -> no straddle
  int t  = (int)(base - (size_t)bc * T_);
  int g = t >> 10, o = t & 1023;           // o multiple of 8
  size_t r0 = (size_t)bc * F_ + g;         // g+1 <= 1407 always valid
  float w1[8], w2[8];
  *(float4*)&w1[0] = *(const float4*)(wf + o);
  *(float4*)&w1[4] = *(const float4*)(wf + o + 4);
  *(float4*)&w2[0] = *(const float4*)(wf + 1024 + o);
  *(float4*)&w2[4] = *(const float4*)(wf + 1024 + o + 4);
  float rv[8];
  if (o < 512) {
    f16x8 a = *(const f16x8*)(tdu + (r0 + 1) * 1024 + o);          // td[g+1][o]
    f16x8 b = *(const f16x8*)(tdu + r0 * 1024 + 512 + o);          // td[g][1024+o]
#pragma unroll
    for (int i = 0; i < 8; i++)
      rv[i] = w1[i] * (float)a[i] + w2[i] * (float)b[i];
  } else {
    f16x8 a = *(const f16x8*)(tdu + (r0 + 1) * 1024 + (1016 - o)); // rev: 1023-(o+i)
    f16x8 b = *(const f16x8*)(tdu + r0 * 1024 + (1528 - o));       // rev: 1535-(o+i)
#pragma unroll
    for (int i = 0; i < 8; i++)
      rv[i] = w2[i] * (float)b[7 - i] - w1[i] * (float)a[7 - i];
  }
  float4 v0, v1;
  v0.x = rv[0]; v0.y = rv[1]; v0.z = rv[2]; v0.w = rv[3];
  v1.x = rv[4]; v1.y = rv[5]; v1.z = rv[6]; v1.w = rv[7];
  *(float4*)(out + base)     = v0;
  *(float4*)(out + base + 4) = v1;
}

// ------------------------------------------------------------------ launch --
extern "C" void kernel_launch(void* const* d_in, const int* in_sizes, int n_in,
                              void* d_out, int out_size, void* d_ws, size_t ws_size,
                              hipStream_t stream) {
  const float* audio = (const float*)d_in[0];
  float* out = (float*)d_out;
  char* wsb  = (char*)d_ws;
  float*    cf  = (float*)(wsb + OFF_CF);
  _Float16* dqh = (_Float16*)(wsb + OFF_DQ);
  _Float16* tdh = (_Float16*)(wsb + OFF_CF);   // cf is dead after quantize

  init_tables<<<(2097152 + 2048 + 255) / 256, 256, 0, stream>>>(wsb);
  fwd_mfma<<<1408, 256, 0, stream>>>(audio, wsb, cf);
  quantize<<<(B_ * F_) / 4, 256, 0, stream>>>(cf, dqh);
  inv_gemm<<<704, 256, 0, stream>>>(wsb, tdh);
  ola<<<(B_ * C_ * T_) / (256 * 8), 256, 0, stream>>>(wsb, out);
}